// Round 10
// baseline (1970.659 us; speedup 1.0000x reference)
//
#include <hip/hip_runtime.h>

#define B_ 8
#define C_ 256
#define H_ 64
#define W_ 64
#define HW_ 4096
#define A_ 9
#define SITES 36864      // A_*HW_
#define NPOST 1000
#define XCLIPF 4.1351666f   // (float)4.135166556742356
#define IMGF 1024.0f
#define PROW 68             // padded row width (floats), 16B-multiple
#define PCH  (65 * PROW)    // padded channel stride (65 rows: 1 zero + 64 data)
#define PB_  ((256 * 65 + 1) * PROW)  // floats per padded batch

__device__ inline unsigned keyf(float v) {
  unsigned u = __float_as_uint(v);
  return (u & 0x80000000u) ? ~u : (u | 0x80000000u);  // ascending uint == ascending float
}

// ---------------- K0: prepad x into zero-haloed layout (unchanged, validated) ----------------
__global__ __launch_bounds__(256) void prepad(
    const float* __restrict__ x, float* __restrict__ xpad, int total) {
  int idx = blockIdx.x * 256 + threadIdx.x;
  if (idx >= total) return;
  int b = idx / PB_;
  int rem = idx - b * PB_;
  int R = rem / PROW;
  int col = rem - R * PROW;
  int rr = R % 65;
  float v = 0.f;
  if (rr != 0 && col >= 1 && col <= 64) {
    int ci = R / 65;
    v = x[(size_t)b * C_ * HW_ + (size_t)ci * HW_ + (size_t)(rr - 1) * W_ + (col - 1)];
  }
  xpad[idx] = v;
}

// ---------------- K1: 3x3 conv + bias + relu, bit-exact f32, TAP-SPLIT ----------------
// 3 threads per 8-px group: thread r in {0,1,2} owns kernel-row r's 3 taps.
// Each per-tap fmaf chain over ci (ascending) lives entirely in one thread -> bit-identical
// to the validated kernels. Final sum reassembled by r=0 in the literal order
// 0 + p0 + p1 + ... + p8 + bias (left-assoc), then relu. Zero-pad taps = exact no-ops.
// Block: 768 threads = 3 tap-rows x 256 pixel-groups (32 rows x 8 chunks, half image).
// grid: B_*C_*2. Per iter per thread: 3 loads (1 addr reg) + 24 FMA; ~48 VGPR -> 24 waves/CU.
__global__ __launch_bounds__(768) void conv3_tap(
    const float* __restrict__ xpad, const float* __restrict__ w,
    const float* __restrict__ bias, float* __restrict__ feats) {
#pragma clang fp contract(off)
  int b    = blockIdx.x >> 9;
  int co   = (blockIdx.x >> 1) & 255;
  int half = blockIdx.x & 1;
  int t = threadIdx.x;
  int r = t >> 8;                       // 0,1,2 (wave-uniform: 4 waves per r)
  int g = t & 255;                      // pixel group
  int gr = (half << 5) + (g >> 3);      // output row 0..63
  int c0 = (g & 7) << 3;                // window start col (16B aligned in xpad)
  // window row for tap-row r of output row gr, channel ci: buffer row ci*65 + gr + r
  const float* q = xpad + (size_t)b * PB_ + (size_t)(gr + r) * PROW + c0;
  const float* wp = w + (size_t)co * (C_ * 9) + 3 * r;   // wave-uniform

  float acc[8][3];
#pragma unroll
  for (int p = 0; p < 8; ++p)
#pragma unroll
    for (int j = 0; j < 3; ++j) acc[p][j] = 0.f;

  for (int ci = 0; ci < C_; ++ci) {
    float4 A  = *(const float4*)(q);
    float4 Bv = *(const float4*)(q + 4);
    float2 Cv = *(const float2*)(q + 8);
    q += PCH;
    float X[10] = {A.x, A.y, A.z, A.w, Bv.x, Bv.y, Bv.z, Bv.w, Cv.x, Cv.y};
    float w0 = wp[ci * 9 + 0], w1 = wp[ci * 9 + 1], w2 = wp[ci * 9 + 2];  // s_load
#pragma unroll
    for (int p = 0; p < 8; ++p) {
      acc[p][0] = fmaf(w0, X[p],     acc[p][0]);
      acc[p][1] = fmaf(w1, X[p + 1], acc[p][1]);
      acc[p][2] = fmaf(w2, X[p + 2], acc[p][2]);
    }
  }

  __shared__ float lds[512 * 25];       // writers r=1,2; stride 25 -> conflict-free
  if (r > 0) {
    float* dst = &lds[(((r - 1) << 8) + g) * 25];
#pragma unroll
    for (int p = 0; p < 8; ++p)
#pragma unroll
      for (int j = 0; j < 3; ++j) dst[p * 3 + j] = acc[p][j];
  }
  __syncthreads();
  if (r == 0) {
    float bv = bias[co];
    const float* p1 = &lds[g * 25];
    const float* p2 = &lds[(256 + g) * 25];
    float ov[8];
#pragma unroll
    for (int p = 0; p < 8; ++p) {
      float a = 0.f;                    // literal validated order: 0+p0+...+p8+bias
      a = a + acc[p][0];
      a = a + acc[p][1];
      a = a + acc[p][2];
      a = a + p1[p * 3 + 0];
      a = a + p1[p * 3 + 1];
      a = a + p1[p * 3 + 2];
      a = a + p2[p * 3 + 0];
      a = a + p2[p * 3 + 1];
      a = a + p2[p * 3 + 2];
      a = a + bv;
      ov[p] = a > 0.f ? a : 0.f;
    }
    float4* fo = (float4*)(feats + ((size_t)b * C_ + co) * HW_ + (size_t)gr * W_ + c0);
    fo[0] = make_float4(ov[0], ov[1], ov[2], ov[3]);
    fo[1] = make_float4(ov[4], ov[5], ov[6], ov[7]);
  }
}

// ---------------- K2: 1x1 convs, 9-way channel split (5 chains/thread), bit-exact ----------------
// gidx -> (cgrp, b, hw); cgrp wave-uniform (32768 % 64 == 0). Each channel's fmaf chain
// over ci ascending is identical to the validated conv1_fused.
__global__ __launch_bounds__(256) void conv1_split(
    const float* __restrict__ feats,
    const float* __restrict__ box_w, const float* __restrict__ box_b,
    const float* __restrict__ obj_w, const float* __restrict__ obj_b,
    float* __restrict__ tbox, float* __restrict__ scores) {
#pragma clang fp contract(off)
  int gidx = blockIdx.x * 256 + threadIdx.x;   // [0, 9*B_*HW_)
  int cgrp = gidx >> 15;                        // 0..8
  int rem  = gidx & 32767;
  int b  = rem >> 12;
  int hw = rem & 4095;
  int cbase = cgrp * 5;
  const float* f = feats + (size_t)b * C_ * HW_ + hw;
  const float* wrow[5];
#pragma unroll
  for (int jj = 0; jj < 5; ++jj) {
    int c = cbase + jj;
    wrow[jj] = (c < 36) ? (box_w + (size_t)c * C_) : (obj_w + (size_t)(c - 36) * C_);
  }
  float acc[5];
#pragma unroll
  for (int jj = 0; jj < 5; ++jj) acc[jj] = 0.f;
  for (int ci = 0; ci < C_; ++ci) {
    float fv = f[(size_t)ci * HW_];
#pragma unroll
    for (int jj = 0; jj < 5; ++jj)
      acc[jj] = fmaf(wrow[jj][ci], fv, acc[jj]);
  }
#pragma unroll
  for (int jj = 0; jj < 5; ++jj) {
    int c = cbase + jj;
    if (c < 36) {
      int k = c / 9, a = c - k * 9;
      tbox[(size_t)b * 4 * SITES + (size_t)k * SITES + (size_t)a * HW_ + hw] = acc[jj] + box_b[c];
    } else {
      int a = c - 36;
      scores[(size_t)b * SITES + (size_t)a * HW_ + hw] = acc[jj] + obj_b[a];
    }
  }
}

// ---------------- K3: exact radix-select of the 1000th-smallest key per batch ----------------
__global__ __launch_bounds__(1024) void radix_select(
    const float* __restrict__ scores, unsigned* __restrict__ Kout,
    int* __restrict__ needEq, int* __restrict__ cnt, int* __restrict__ eqCnt) {
  int b = blockIdx.x;
  const float* s = scores + (size_t)b * SITES;
  __shared__ unsigned hist[256];
  __shared__ unsigned sh_prefix, sh_mask, sh_cless;
  __shared__ int sh_target;
  if (threadIdx.x == 0) { sh_prefix = 0; sh_mask = 0; sh_target = NPOST - 1; sh_cless = 0; }
  for (int shift = 24; shift >= 0; shift -= 8) {
    if (threadIdx.x < 256) hist[threadIdx.x] = 0;
    __syncthreads();
    unsigned prefix = sh_prefix, mask = sh_mask;
    for (int i = threadIdx.x; i < SITES; i += 1024) {
      unsigned k = keyf(s[i]);
      if ((k & mask) == prefix) atomicAdd(&hist[(k >> shift) & 255u], 1u);
    }
    __syncthreads();
    if (threadIdx.x == 0) {
      unsigned cum = 0; int t = sh_target; int v = 0;
      for (; v < 256; ++v) {
        unsigned h = hist[v];
        if (cum + h > (unsigned)t) break;
        cum += h;
      }
      sh_prefix |= ((unsigned)v) << shift;
      sh_mask   |= 0xFFu << shift;
      sh_target  = t - (int)cum;
      sh_cless  += cum;
    }
    __syncthreads();
  }
  if (threadIdx.x == 0) {
    Kout[b] = sh_prefix;
    needEq[b] = NPOST - (int)sh_cless;
    cnt[b] = 0;
    eqCnt[b] = 0;
  }
}

// ---------------- K4: compact k<K sites; collect k==K sites ----------------
__global__ __launch_bounds__(256) void compact_sel(
    const float* __restrict__ scores, const unsigned* __restrict__ Kout,
    int* __restrict__ cnt, int* __restrict__ sel,
    int* __restrict__ eqCnt, int* __restrict__ eqList) {
  int b = blockIdx.x / 144;
  int i = (blockIdx.x % 144) * 256 + threadIdx.x;
  unsigned K = Kout[b];
  unsigned k = keyf(scores[(size_t)b * SITES + i]);
  if (k < K) {
    int pos = atomicAdd(&cnt[b], 1);
    sel[b * 1024 + pos] = i;               // arbitrary order: order_decode re-sorts
  } else if (k == K) {
    int e = atomicAdd(&eqCnt[b], 1);
    if (e < 4096) eqList[b * 4096 + e] = i;
  }
}

// ---------------- K4b: take the needEq smallest-index equal-key sites ----------------
__global__ __launch_bounds__(256) void fix_eq(
    const int* __restrict__ cnt, const int* __restrict__ needEq,
    const int* __restrict__ eqCnt, const int* __restrict__ eqList,
    int* __restrict__ sel) {
  int b = blockIdx.x;
  int E = eqCnt[b]; if (E > 4096) E = 4096;
  int need = needEq[b];
  int base = cnt[b];
  const int* el = eqList + b * 4096;
  for (int t = threadIdx.x; t < E; t += 256) {
    int site = el[t];
    int rank = 0;
    for (int q = 0; q < E; ++q) rank += (el[q] < site);
    if (rank < need) sel[b * 1024 + base + rank] = site;
  }
}

// ---------------- K5: descending order of the selected 1000 + fused decode ----------------
__global__ __launch_bounds__(1024) void order_decode(
    const float* __restrict__ scores, const int* __restrict__ sel,
    const float* __restrict__ tbox, float* __restrict__ s2, float* __restrict__ b2) {
#pragma clang fp contract(off)
  int b = blockIdx.x;
  int r = threadIdx.x;
  __shared__ float ss[NPOST];
  __shared__ int st[NPOST];
  if (r < NPOST) {
    int site = sel[b * 1024 + r];
    st[r] = site;
    ss[r] = scores[(size_t)b * SITES + site];
  }
  __syncthreads();
  if (r < NPOST) {
    float sr = ss[r]; int sir = st[r];
    int d = 0;
    for (int q = 0; q < NPOST; ++q) {
      float sq = ss[q];
      d += (int)((sq > sr) || (sq == sr && st[q] < sir));
    }
    s2[(size_t)b * NPOST + d] = sr;
    int site = sir;
    int a = site / HW_;
    int hw = site - a * HW_;
    int h = hw / W_, wc = hw - h * W_;
    int sidx = a / 3, ridx = a - sidx * 3;
    float scale = (sidx == 0) ? 128.f : ((sidx == 1) ? 256.f : 512.f);
    float ratio = (ridx == 0) ? 0.5f : ((ridx == 1) ? 1.0f : 2.0f);
    float sq = sqrtf(ratio);
    float wsa = scale / sq;
    float hsa = scale * sq;
    float cx = ((float)wc + 0.5f) * 16.f;
    float cy = ((float)h + 0.5f) * 16.f;
    float ax1 = cx - wsa * 0.5f;
    float ay1 = cy - hsa * 0.5f;
    float ax2 = cx + wsa * 0.5f;
    float ay2 = cy + hsa * 0.5f;
    float aw = ax2 - ax1, ah = ay2 - ay1;
    float m1 = 0.5f * aw, m2 = 0.5f * ah;
    float acx = ax1 + m1, acy = ay1 + m2;
    const float* tb = tbox + (size_t)b * 4 * SITES + site;
    float t0 = tb[0];
    float t1 = tb[SITES];
    float t2 = tb[2 * (size_t)SITES];
    float t3 = tb[3 * (size_t)SITES];
    if (t2 < -XCLIPF) t2 = -XCLIPF;
    if (t2 > XCLIPF) t2 = XCLIPF;
    if (t3 < -XCLIPF) t3 = -XCLIPF;
    if (t3 > XCLIPF) t3 = XCLIPF;
    float pm0 = t0 * aw;  float pcx = pm0 + acx;
    float pm1 = t1 * ah;  float pcy = pm1 + acy;
    float pw = expf(t2) * aw;
    float ph = expf(t3) * ah;
    float hw0 = 0.5f * pw, hh0 = 0.5f * ph;
    float x1 = pcx - hw0, y1 = pcy - hh0;
    float x2 = pcx + hw0, y2 = pcy + hh0;
    x1 = x1 < 0.f ? 0.f : (x1 > IMGF ? IMGF : x1);
    y1 = y1 < 0.f ? 0.f : (y1 > IMGF ? IMGF : y1);
    x2 = x2 < 0.f ? 0.f : (x2 > IMGF ? IMGF : x2);
    y2 = y2 < 0.f ? 0.f : (y2 > IMGF ? IMGF : y2);
    float* o = b2 + ((size_t)b * NPOST + d) * 4;
    o[0] = x1; o[1] = y1; o[2] = x2; o[3] = y2;
  }
}

// ---------------- K6a: suppression bitmask (j > i && IoU > 0.7), f32, exact op order ----------------
__global__ __launch_bounds__(256) void mask_kernel(
    const float* __restrict__ b2, unsigned long long* __restrict__ sup) {
#pragma clang fp contract(off)
  int b = blockIdx.x / 63;
  int i0 = (blockIdx.x % 63) * 16;
  __shared__ float bs[NPOST * 4];
  __shared__ float area[NPOST];
  for (int t = threadIdx.x; t < NPOST * 4; t += 256) bs[t] = b2[(size_t)b * NPOST * 4 + t];
  __syncthreads();
  for (int t = threadIdx.x; t < NPOST; t += 256)
    area[t] = (bs[t * 4 + 2] - bs[t * 4]) * (bs[t * 4 + 3] - bs[t * 4 + 1]);
  __syncthreads();
  int i = i0 + (threadIdx.x >> 4);
  int wd = threadIdx.x & 15;
  if (i >= NPOST) return;
  float ax1 = bs[i * 4], ay1 = bs[i * 4 + 1], ax2 = bs[i * 4 + 2], ay2 = bs[i * 4 + 3];
  float aa = area[i];
  unsigned long long m = 0;
  for (int bit = 0; bit < 64; ++bit) {
    int j = wd * 64 + bit;
    if (j > i && j < NPOST) {
      float lx = fmaxf(ax1, bs[j * 4]);
      float ly = fmaxf(ay1, bs[j * 4 + 1]);
      float rx = fminf(ax2, bs[j * 4 + 2]);
      float ry = fminf(ay2, bs[j * 4 + 3]);
      float iw = rx - lx; if (iw < 0.f) iw = 0.f;
      float ih = ry - ly; if (ih < 0.f) ih = 0.f;
      float inter = iw * ih;
      float denom = (aa + area[j]) - inter;
      float iou = inter / denom;
      if (iou > 0.7f) m |= 1ull << bit;
    }
  }
  sup[((size_t)b * NPOST + i) * 16 + wd] = m;
}

// ---------------- K6b: wave-synchronous NMS scan + compaction + zero fill ----------------
__global__ __launch_bounds__(64) void nms_out(
    const unsigned long long* __restrict__ sup, const float* __restrict__ b2,
    const float* __restrict__ s2, float* __restrict__ out) {
  int b = blockIdx.x;
  int lane = threadIdx.x;
  unsigned long long kw = 0;
  if (lane < 16) kw = (lane < 15) ? ~0ull : ((1ull << 40) - 1);  // bits 960..999 valid
  const unsigned long long* ms = sup + (size_t)b * NPOST * 16;
  unsigned long long m_cur = (lane < 16) ? ms[lane] : 0ull;
  for (int i = 0; i < NPOST; ++i) {
    unsigned long long m_nxt = (i + 1 < NPOST && lane < 16) ? ms[(size_t)(i + 1) * 16 + lane] : 0ull;
    unsigned long long w = __shfl(kw, i >> 6, 64);
    if ((w >> (i & 63)) & 1ull) {
      if (lane < 16) kw &= ~m_cur;
    }
    m_cur = m_nxt;
  }
  __shared__ unsigned long long keeps[16];
  if (lane < 16) keeps[lane] = kw;
  __syncthreads();
  int total = 0;
#pragma unroll
  for (int k = 0; k < 16; ++k) total += __popcll(keeps[k]);
  for (int i = lane; i < NPOST; i += 64) {
    int w = i >> 6;
    int before = 0;
    for (int k = 0; k < w; ++k) before += __popcll(keeps[k]);
    before += __popcll(keeps[w] & ((1ull << (i & 63)) - 1));
    bool kept = (keeps[w] >> (i & 63)) & 1ull;
    if (kept) {
      size_t ob = (size_t)b * (NPOST * 5) + (size_t)before * 5;
      const float* src = b2 + ((size_t)b * NPOST + i) * 4;
      out[ob + 0] = src[0];
      out[ob + 1] = src[1];
      out[ob + 2] = src[2];
      out[ob + 3] = src[3];
      out[ob + 4] = s2[(size_t)b * NPOST + i];
    }
    if (i >= total) {
      size_t ob = (size_t)b * (NPOST * 5) + (size_t)i * 5;
      for (int c = 0; c < 5; ++c) out[ob + c] = 0.f;
    }
  }
}

extern "C" void kernel_launch(void* const* d_in, const int* in_sizes, int n_in,
                              void* d_out, int out_size, void* d_ws, size_t ws_size,
                              hipStream_t stream) {
  const float *x = nullptr, *conv_w = nullptr, *conv_b = nullptr,
              *box_w = nullptr, *box_b = nullptr, *obj_w = nullptr, *obj_b = nullptr;
  for (int i = 0; i < n_in; ++i) {
    switch (in_sizes[i]) {
      case 8388608: x = (const float*)d_in[i]; break;
      case 589824:  conv_w = (const float*)d_in[i]; break;
      case 256:     conv_b = (const float*)d_in[i]; break;
      case 9216:    box_w = (const float*)d_in[i]; break;
      case 36:      box_b = (const float*)d_in[i]; break;
      case 2304:    obj_w = (const float*)d_in[i]; break;
      case 9:       obj_b = (const float*)d_in[i]; break;
    }
  }
  float* out = (float*)d_out;

  char* p = (char*)d_ws;
  auto alloc = [&](size_t n) { char* q = p; p += (n + 255) & ~255ull; return (void*)q; };
  float* xpad   = (float*)alloc((size_t)B_ * PB_ * 4);            // 36.21 MB
  float* feats  = (float*)alloc((size_t)B_ * C_ * HW_ * 4);       // 33.55 MB
  float* tbox   = (float*)alloc((size_t)B_ * 4 * SITES * 4);      // 4.72 MB
  float* scores = (float*)alloc((size_t)B_ * SITES * 4);          // 1.18 MB
  unsigned* Kout = (unsigned*)alloc(B_ * 4);
  int* needEq    = (int*)alloc(B_ * 4);
  int* cnt       = (int*)alloc(B_ * 4);
  int* eqCnt     = (int*)alloc(B_ * 4);
  int* eqList    = (int*)alloc((size_t)B_ * 4096 * 4);
  int* sel       = (int*)alloc((size_t)B_ * 1024 * 4);
  float* s2      = (float*)alloc((size_t)B_ * NPOST * 4);
  float* b2      = (float*)alloc((size_t)B_ * NPOST * 4 * 4);
  unsigned long long* sup = (unsigned long long*)alloc((size_t)B_ * NPOST * 16 * 8); // 1.02 MB

  int prepad_total = B_ * PB_;
  hipLaunchKernelGGL(prepad, dim3((prepad_total + 255) / 256), dim3(256), 0, stream,
                     x, xpad, prepad_total);
  hipLaunchKernelGGL(conv3_tap, dim3(B_ * C_ * 2), dim3(768), 0, stream,
                     xpad, conv_w, conv_b, feats);
  hipLaunchKernelGGL(conv1_split, dim3(9 * B_ * HW_ / 256), dim3(256), 0, stream,
                     feats, box_w, box_b, obj_w, obj_b, tbox, scores);
  hipLaunchKernelGGL(radix_select, dim3(B_), dim3(1024), 0, stream,
                     scores, Kout, needEq, cnt, eqCnt);
  hipLaunchKernelGGL(compact_sel, dim3(B_ * 144), dim3(256), 0, stream,
                     scores, Kout, cnt, sel, eqCnt, eqList);
  hipLaunchKernelGGL(fix_eq, dim3(B_), dim3(256), 0, stream,
                     cnt, needEq, eqCnt, eqList, sel);
  hipLaunchKernelGGL(order_decode, dim3(B_), dim3(1024), 0, stream,
                     scores, sel, tbox, s2, b2);
  hipLaunchKernelGGL(mask_kernel, dim3(B_ * 63), dim3(256), 0, stream, b2, sup);
  hipLaunchKernelGGL(nms_out, dim3(B_), dim3(64), 0, stream, sup, b2, s2, out);
}

// Round 11
// 1804.850 us; speedup vs baseline: 1.0919x; 1.0919x over previous
//
#include <hip/hip_runtime.h>

#define B_ 8
#define C_ 256
#define H_ 64
#define W_ 64
#define HW_ 4096
#define A_ 9
#define SITES 36864      // A_*HW_
#define NPOST 1000
#define XCLIPF 4.1351666f   // (float)4.135166556742356
#define IMGF 1024.0f
#define PROW 68             // padded row width (floats), 16B-multiple
#define PCH  (65 * PROW)    // padded channel stride (65 rows: 1 zero + 64 data)
#define PB_  ((256 * 65 + 1) * PROW)  // floats per padded batch

__device__ inline unsigned keyf(float v) {
  unsigned u = __float_as_uint(v);
  return (u & 0x80000000u) ? ~u : (u | 0x80000000u);  // ascending uint == ascending float
}

// ---------------- K0: prepad x into zero-haloed layout (unchanged, validated) ----------------
__global__ __launch_bounds__(256) void prepad(
    const float* __restrict__ x, float* __restrict__ xpad, int total) {
  int idx = blockIdx.x * 256 + threadIdx.x;
  if (idx >= total) return;
  int b = idx / PB_;
  int rem = idx - b * PB_;
  int R = rem / PROW;
  int col = rem - R * PROW;
  int rr = R % 65;
  float v = 0.f;
  if (rr != 0 && col >= 1 && col <= 64) {
    int ci = R / 65;
    v = x[(size_t)b * C_ * HW_ + (size_t)ci * HW_ + (size_t)(rr - 1) * W_ + (col - 1)];
  }
  xpad[idx] = v;
}

// window load: 9 loads off one base with immediate offsets (rows +0, +PROW, +2*PROW)
#define LOAD_WIN(Q, T_, M_, Bo_) do {                                   \
  float4 tA = *(const float4*)(Q);                                      \
  float4 tB = *(const float4*)((Q) + 4);                                \
  float2 tC = *(const float2*)((Q) + 8);                                \
  float4 mA = *(const float4*)((Q) + PROW);                             \
  float4 mB = *(const float4*)((Q) + PROW + 4);                         \
  float2 mC = *(const float2*)((Q) + PROW + 8);                         \
  float4 bA = *(const float4*)((Q) + 2 * PROW);                         \
  float4 bB = *(const float4*)((Q) + 2 * PROW + 4);                     \
  float2 bC = *(const float2*)((Q) + 2 * PROW + 8);                     \
  T_[0]=tA.x; T_[1]=tA.y; T_[2]=tA.z; T_[3]=tA.w; T_[4]=tB.x; T_[5]=tB.y; T_[6]=tB.z; T_[7]=tB.w; T_[8]=tC.x; T_[9]=tC.y; \
  M_[0]=mA.x; M_[1]=mA.y; M_[2]=mA.z; M_[3]=mA.w; M_[4]=mB.x; M_[5]=mB.y; M_[6]=mB.z; M_[7]=mB.w; M_[8]=mC.x; M_[9]=mC.y; \
  Bo_[0]=bA.x; Bo_[1]=bA.y; Bo_[2]=bA.z; Bo_[3]=bA.w; Bo_[4]=bB.x; Bo_[5]=bB.y; Bo_[6]=bB.z; Bo_[7]=bB.w; Bo_[8]=bC.x; Bo_[9]=bC.y; \
} while (0)

// FMA stage: identical op order to the validated kernels (rounds 4-10, absmax 0.0)
#define FMA_STAGE(W9, T_, M_, Bo_) do {                                 \
  _Pragma("unroll")                                                     \
  for (int p = 0; p < 8; ++p) {                                         \
    acc[p][0] = fmaf(W9[0], T_[p],      acc[p][0]);                     \
    acc[p][1] = fmaf(W9[1], T_[p + 1],  acc[p][1]);                     \
    acc[p][2] = fmaf(W9[2], T_[p + 2],  acc[p][2]);                     \
    acc[p][3] = fmaf(W9[3], M_[p],      acc[p][3]);                     \
    acc[p][4] = fmaf(W9[4], M_[p + 1],  acc[p][4]);                     \
    acc[p][5] = fmaf(W9[5], M_[p + 2],  acc[p][5]);                     \
    acc[p][6] = fmaf(W9[6], Bo_[p],     acc[p][6]);                     \
    acc[p][7] = fmaf(W9[7], Bo_[p + 1], acc[p][7]);                     \
    acc[p][8] = fmaf(W9[8], Bo_[p + 2], acc[p][8]);                     \
  }                                                                     \
} while (0)

// ---------------- K1: 3x3 conv + bias + relu, bit-exact f32, PIPELINED pad-loads ----------------
// Structure of round-9 conv3_pad (pure loads, no shfl/cndmask) + two fixes:
//  (a) explicit 2-stage register double-buffer: window for ci+1 / ci+2 is loaded BEFORE
//      the FMA block consuming ci — breaks the load->vmcnt(0)->FMA serial chain;
//  (b) XCD-aware swizzle: blocks with equal blockIdx%8 (same XCD, round-robin heuristic)
//      share one (b,half) 2.26MB input stream -> fits 4MB per-XCD L2 (kills r10's thrash).
// FMA chains & tap-sum order identical to validated kernels; final overread (ci=256) is
// issued but never consumed (lands in adjacent ws buffer, no fault).
// grid: 4096 blocks x 256 threads; 8 px/thread; ~145 VGPR -> 3 waves/SIMD.
__global__ __launch_bounds__(256, 3) void conv3_pipe(
    const float* __restrict__ xpad, const float* __restrict__ w,
    const float* __restrict__ bias, float* __restrict__ feats) {
#pragma clang fp contract(off)
  int i   = blockIdx.x;
  int xcd = i & 7;                       // round-robin XCD heuristic (perf-only)
  int j   = i >> 3;
  int co  = j & 255;
  int g   = (((j >> 8) & 1) << 3) | xcd; // 0..15 = (b,half)
  int b    = g >> 1;
  int half = g & 1;
  int gr = (half << 5) + (threadIdx.x >> 3);   // output row 0..63
  int c0 = (threadIdx.x & 7) << 3;             // window start col (16B aligned)
  const float* q = xpad + (size_t)b * PB_ + (size_t)gr * PROW + c0;
  const float* wp = w + (size_t)co * (C_ * 9);

  float acc[8][9];
#pragma unroll
  for (int p = 0; p < 8; ++p)
#pragma unroll
    for (int t = 0; t < 9; ++t) acc[p][t] = 0.f;

  float T0[10], M0[10], B0[10], T1[10], M1[10], B1[10];
  LOAD_WIN(q, T0, M0, B0); q += PCH;
  for (int ci = 0; ci < C_; ci += 2) {
    LOAD_WIN(q, T1, M1, B1); q += PCH;          // prefetch ci+1
    float w9[9];
#pragma unroll
    for (int t = 0; t < 9; ++t) w9[t] = wp[ci * 9 + t];       // s_load
    FMA_STAGE(w9, T0, M0, B0);                  // consume ci
    LOAD_WIN(q, T0, M0, B0); q += PCH;          // prefetch ci+2 (last one dead)
#pragma unroll
    for (int t = 0; t < 9; ++t) w9[t] = wp[(ci + 1) * 9 + t];
    FMA_STAGE(w9, T1, M1, B1);                  // consume ci+1
  }

  float bv = bias[co];
  float ov[8];
#pragma unroll
  for (int p = 0; p < 8; ++p) {
    float a = 0.f;
#pragma unroll
    for (int t = 0; t < 9; ++t) a = a + acc[p][t];  // tap-ordered, left-assoc
    a = a + bv;
    ov[p] = a > 0.f ? a : 0.f;
  }
  float4* fo = (float4*)(feats + ((size_t)b * C_ + co) * HW_ + (size_t)gr * W_ + c0);
  fo[0] = make_float4(ov[0], ov[1], ov[2], ov[3]);
  fo[1] = make_float4(ov[4], ov[5], ov[6], ov[7]);
}

// ---------------- K2: 1x1 convs, 9-way channel split (5 chains/thread), bit-exact ----------------
__global__ __launch_bounds__(256) void conv1_split(
    const float* __restrict__ feats,
    const float* __restrict__ box_w, const float* __restrict__ box_b,
    const float* __restrict__ obj_w, const float* __restrict__ obj_b,
    float* __restrict__ tbox, float* __restrict__ scores) {
#pragma clang fp contract(off)
  int gidx = blockIdx.x * 256 + threadIdx.x;   // [0, 9*B_*HW_)
  int cgrp = gidx >> 15;                        // 0..8
  int rem  = gidx & 32767;
  int b  = rem >> 12;
  int hw = rem & 4095;
  int cbase = cgrp * 5;
  const float* f = feats + (size_t)b * C_ * HW_ + hw;
  const float* wrow[5];
#pragma unroll
  for (int jj = 0; jj < 5; ++jj) {
    int c = cbase + jj;
    wrow[jj] = (c < 36) ? (box_w + (size_t)c * C_) : (obj_w + (size_t)(c - 36) * C_);
  }
  float acc[5];
#pragma unroll
  for (int jj = 0; jj < 5; ++jj) acc[jj] = 0.f;
  for (int ci = 0; ci < C_; ++ci) {
    float fv = f[(size_t)ci * HW_];
#pragma unroll
    for (int jj = 0; jj < 5; ++jj)
      acc[jj] = fmaf(wrow[jj][ci], fv, acc[jj]);
  }
#pragma unroll
  for (int jj = 0; jj < 5; ++jj) {
    int c = cbase + jj;
    if (c < 36) {
      int k = c / 9, a = c - k * 9;
      tbox[(size_t)b * 4 * SITES + (size_t)k * SITES + (size_t)a * HW_ + hw] = acc[jj] + box_b[c];
    } else {
      int a = c - 36;
      scores[(size_t)b * SITES + (size_t)a * HW_ + hw] = acc[jj] + obj_b[a];
    }
  }
}

// ---------------- K3: exact radix-select of the 1000th-smallest key per batch ----------------
__global__ __launch_bounds__(1024) void radix_select(
    const float* __restrict__ scores, unsigned* __restrict__ Kout,
    int* __restrict__ needEq, int* __restrict__ cnt, int* __restrict__ eqCnt) {
  int b = blockIdx.x;
  const float* s = scores + (size_t)b * SITES;
  __shared__ unsigned hist[256];
  __shared__ unsigned sh_prefix, sh_mask, sh_cless;
  __shared__ int sh_target;
  if (threadIdx.x == 0) { sh_prefix = 0; sh_mask = 0; sh_target = NPOST - 1; sh_cless = 0; }
  for (int shift = 24; shift >= 0; shift -= 8) {
    if (threadIdx.x < 256) hist[threadIdx.x] = 0;
    __syncthreads();
    unsigned prefix = sh_prefix, mask = sh_mask;
    for (int i = threadIdx.x; i < SITES; i += 1024) {
      unsigned k = keyf(s[i]);
      if ((k & mask) == prefix) atomicAdd(&hist[(k >> shift) & 255u], 1u);
    }
    __syncthreads();
    if (threadIdx.x == 0) {
      unsigned cum = 0; int t = sh_target; int v = 0;
      for (; v < 256; ++v) {
        unsigned h = hist[v];
        if (cum + h > (unsigned)t) break;
        cum += h;
      }
      sh_prefix |= ((unsigned)v) << shift;
      sh_mask   |= 0xFFu << shift;
      sh_target  = t - (int)cum;
      sh_cless  += cum;
    }
    __syncthreads();
  }
  if (threadIdx.x == 0) {
    Kout[b] = sh_prefix;
    needEq[b] = NPOST - (int)sh_cless;
    cnt[b] = 0;
    eqCnt[b] = 0;
  }
}

// ---------------- K4: compact k<K sites; collect k==K sites ----------------
__global__ __launch_bounds__(256) void compact_sel(
    const float* __restrict__ scores, const unsigned* __restrict__ Kout,
    int* __restrict__ cnt, int* __restrict__ sel,
    int* __restrict__ eqCnt, int* __restrict__ eqList) {
  int b = blockIdx.x / 144;
  int i = (blockIdx.x % 144) * 256 + threadIdx.x;
  unsigned K = Kout[b];
  unsigned k = keyf(scores[(size_t)b * SITES + i]);
  if (k < K) {
    int pos = atomicAdd(&cnt[b], 1);
    sel[b * 1024 + pos] = i;               // arbitrary order: order_decode re-sorts
  } else if (k == K) {
    int e = atomicAdd(&eqCnt[b], 1);
    if (e < 4096) eqList[b * 4096 + e] = i;
  }
}

// ---------------- K4b: take the needEq smallest-index equal-key sites ----------------
__global__ __launch_bounds__(256) void fix_eq(
    const int* __restrict__ cnt, const int* __restrict__ needEq,
    const int* __restrict__ eqCnt, const int* __restrict__ eqList,
    int* __restrict__ sel) {
  int b = blockIdx.x;
  int E = eqCnt[b]; if (E > 4096) E = 4096;
  int need = needEq[b];
  int base = cnt[b];
  const int* el = eqList + b * 4096;
  for (int t = threadIdx.x; t < E; t += 256) {
    int site = el[t];
    int rank = 0;
    for (int q = 0; q < E; ++q) rank += (el[q] < site);
    if (rank < need) sel[b * 1024 + base + rank] = site;
  }
}

// ---------------- K5: descending order of the selected 1000 + fused decode ----------------
__global__ __launch_bounds__(1024) void order_decode(
    const float* __restrict__ scores, const int* __restrict__ sel,
    const float* __restrict__ tbox, float* __restrict__ s2, float* __restrict__ b2) {
#pragma clang fp contract(off)
  int b = blockIdx.x;
  int r = threadIdx.x;
  __shared__ float ss[NPOST];
  __shared__ int st[NPOST];
  if (r < NPOST) {
    int site = sel[b * 1024 + r];
    st[r] = site;
    ss[r] = scores[(size_t)b * SITES + site];
  }
  __syncthreads();
  if (r < NPOST) {
    float sr = ss[r]; int sir = st[r];
    int d = 0;
    for (int q = 0; q < NPOST; ++q) {
      float sq = ss[q];
      d += (int)((sq > sr) || (sq == sr && st[q] < sir));
    }
    s2[(size_t)b * NPOST + d] = sr;
    int site = sir;
    int a = site / HW_;
    int hw = site - a * HW_;
    int h = hw / W_, wc = hw - h * W_;
    int sidx = a / 3, ridx = a - sidx * 3;
    float scale = (sidx == 0) ? 128.f : ((sidx == 1) ? 256.f : 512.f);
    float ratio = (ridx == 0) ? 0.5f : ((ridx == 1) ? 1.0f : 2.0f);
    float sq = sqrtf(ratio);
    float wsa = scale / sq;
    float hsa = scale * sq;
    float cx = ((float)wc + 0.5f) * 16.f;
    float cy = ((float)h + 0.5f) * 16.f;
    float ax1 = cx - wsa * 0.5f;
    float ay1 = cy - hsa * 0.5f;
    float ax2 = cx + wsa * 0.5f;
    float ay2 = cy + hsa * 0.5f;
    float aw = ax2 - ax1, ah = ay2 - ay1;
    float m1 = 0.5f * aw, m2 = 0.5f * ah;
    float acx = ax1 + m1, acy = ay1 + m2;
    const float* tb = tbox + (size_t)b * 4 * SITES + site;
    float t0 = tb[0];
    float t1 = tb[SITES];
    float t2 = tb[2 * (size_t)SITES];
    float t3 = tb[3 * (size_t)SITES];
    if (t2 < -XCLIPF) t2 = -XCLIPF;
    if (t2 > XCLIPF) t2 = XCLIPF;
    if (t3 < -XCLIPF) t3 = -XCLIPF;
    if (t3 > XCLIPF) t3 = XCLIPF;
    float pm0 = t0 * aw;  float pcx = pm0 + acx;
    float pm1 = t1 * ah;  float pcy = pm1 + acy;
    float pw = expf(t2) * aw;
    float ph = expf(t3) * ah;
    float hw0 = 0.5f * pw, hh0 = 0.5f * ph;
    float x1 = pcx - hw0, y1 = pcy - hh0;
    float x2 = pcx + hw0, y2 = pcy + hh0;
    x1 = x1 < 0.f ? 0.f : (x1 > IMGF ? IMGF : x1);
    y1 = y1 < 0.f ? 0.f : (y1 > IMGF ? IMGF : y1);
    x2 = x2 < 0.f ? 0.f : (x2 > IMGF ? IMGF : x2);
    y2 = y2 < 0.f ? 0.f : (y2 > IMGF ? IMGF : y2);
    float* o = b2 + ((size_t)b * NPOST + d) * 4;
    o[0] = x1; o[1] = y1; o[2] = x2; o[3] = y2;
  }
}

// ---------------- K6a: suppression bitmask (j > i && IoU > 0.7), f32, exact op order ----------------
__global__ __launch_bounds__(256) void mask_kernel(
    const float* __restrict__ b2, unsigned long long* __restrict__ sup) {
#pragma clang fp contract(off)
  int b = blockIdx.x / 63;
  int i0 = (blockIdx.x % 63) * 16;
  __shared__ float bs[NPOST * 4];
  __shared__ float area[NPOST];
  for (int t = threadIdx.x; t < NPOST * 4; t += 256) bs[t] = b2[(size_t)b * NPOST * 4 + t];
  __syncthreads();
  for (int t = threadIdx.x; t < NPOST; t += 256)
    area[t] = (bs[t * 4 + 2] - bs[t * 4]) * (bs[t * 4 + 3] - bs[t * 4 + 1]);
  __syncthreads();
  int i = i0 + (threadIdx.x >> 4);
  int wd = threadIdx.x & 15;
  if (i >= NPOST) return;
  float ax1 = bs[i * 4], ay1 = bs[i * 4 + 1], ax2 = bs[i * 4 + 2], ay2 = bs[i * 4 + 3];
  float aa = area[i];
  unsigned long long m = 0;
  for (int bit = 0; bit < 64; ++bit) {
    int j = wd * 64 + bit;
    if (j > i && j < NPOST) {
      float lx = fmaxf(ax1, bs[j * 4]);
      float ly = fmaxf(ay1, bs[j * 4 + 1]);
      float rx = fminf(ax2, bs[j * 4 + 2]);
      float ry = fminf(ay2, bs[j * 4 + 3]);
      float iw = rx - lx; if (iw < 0.f) iw = 0.f;
      float ih = ry - ly; if (ih < 0.f) ih = 0.f;
      float inter = iw * ih;
      float denom = (aa + area[j]) - inter;
      float iou = inter / denom;
      if (iou > 0.7f) m |= 1ull << bit;
    }
  }
  sup[((size_t)b * NPOST + i) * 16 + wd] = m;
}

// ---------------- K6b: wave-synchronous NMS scan + compaction + zero fill ----------------
__global__ __launch_bounds__(64) void nms_out(
    const unsigned long long* __restrict__ sup, const float* __restrict__ b2,
    const float* __restrict__ s2, float* __restrict__ out) {
  int b = blockIdx.x;
  int lane = threadIdx.x;
  unsigned long long kw = 0;
  if (lane < 16) kw = (lane < 15) ? ~0ull : ((1ull << 40) - 1);  // bits 960..999 valid
  const unsigned long long* ms = sup + (size_t)b * NPOST * 16;
  unsigned long long m_cur = (lane < 16) ? ms[lane] : 0ull;
  for (int i = 0; i < NPOST; ++i) {
    unsigned long long m_nxt = (i + 1 < NPOST && lane < 16) ? ms[(size_t)(i + 1) * 16 + lane] : 0ull;
    unsigned long long w = __shfl(kw, i >> 6, 64);
    if ((w >> (i & 63)) & 1ull) {
      if (lane < 16) kw &= ~m_cur;
    }
    m_cur = m_nxt;
  }
  __shared__ unsigned long long keeps[16];
  if (lane < 16) keeps[lane] = kw;
  __syncthreads();
  int total = 0;
#pragma unroll
  for (int k = 0; k < 16; ++k) total += __popcll(keeps[k]);
  for (int i = lane; i < NPOST; i += 64) {
    int w = i >> 6;
    int before = 0;
    for (int k = 0; k < w; ++k) before += __popcll(keeps[k]);
    before += __popcll(keeps[w] & ((1ull << (i & 63)) - 1));
    bool kept = (keeps[w] >> (i & 63)) & 1ull;
    if (kept) {
      size_t ob = (size_t)b * (NPOST * 5) + (size_t)before * 5;
      const float* src = b2 + ((size_t)b * NPOST + i) * 4;
      out[ob + 0] = src[0];
      out[ob + 1] = src[1];
      out[ob + 2] = src[2];
      out[ob + 3] = src[3];
      out[ob + 4] = s2[(size_t)b * NPOST + i];
    }
    if (i >= total) {
      size_t ob = (size_t)b * (NPOST * 5) + (size_t)i * 5;
      for (int c = 0; c < 5; ++c) out[ob + c] = 0.f;
    }
  }
}

extern "C" void kernel_launch(void* const* d_in, const int* in_sizes, int n_in,
                              void* d_out, int out_size, void* d_ws, size_t ws_size,
                              hipStream_t stream) {
  const float *x = nullptr, *conv_w = nullptr, *conv_b = nullptr,
              *box_w = nullptr, *box_b = nullptr, *obj_w = nullptr, *obj_b = nullptr;
  for (int i = 0; i < n_in; ++i) {
    switch (in_sizes[i]) {
      case 8388608: x = (const float*)d_in[i]; break;
      case 589824:  conv_w = (const float*)d_in[i]; break;
      case 256:     conv_b = (const float*)d_in[i]; break;
      case 9216:    box_w = (const float*)d_in[i]; break;
      case 36:      box_b = (const float*)d_in[i]; break;
      case 2304:    obj_w = (const float*)d_in[i]; break;
      case 9:       obj_b = (const float*)d_in[i]; break;
    }
  }
  float* out = (float*)d_out;

  char* p = (char*)d_ws;
  auto alloc = [&](size_t n) { char* q = p; p += (n + 255) & ~255ull; return (void*)q; };
  float* xpad   = (float*)alloc((size_t)B_ * PB_ * 4);            // 36.21 MB
  float* feats  = (float*)alloc((size_t)B_ * C_ * HW_ * 4);       // 33.55 MB (also absorbs the one dead overread)
  float* tbox   = (float*)alloc((size_t)B_ * 4 * SITES * 4);      // 4.72 MB
  float* scores = (float*)alloc((size_t)B_ * SITES * 4);          // 1.18 MB
  unsigned* Kout = (unsigned*)alloc(B_ * 4);
  int* needEq    = (int*)alloc(B_ * 4);
  int* cnt       = (int*)alloc(B_ * 4);
  int* eqCnt     = (int*)alloc(B_ * 4);
  int* eqList    = (int*)alloc((size_t)B_ * 4096 * 4);
  int* sel       = (int*)alloc((size_t)B_ * 1024 * 4);
  float* s2      = (float*)alloc((size_t)B_ * NPOST * 4);
  float* b2      = (float*)alloc((size_t)B_ * NPOST * 4 * 4);
  unsigned long long* sup = (unsigned long long*)alloc((size_t)B_ * NPOST * 16 * 8); // 1.02 MB

  int prepad_total = B_ * PB_;
  hipLaunchKernelGGL(prepad, dim3((prepad_total + 255) / 256), dim3(256), 0, stream,
                     x, xpad, prepad_total);
  hipLaunchKernelGGL(conv3_pipe, dim3(B_ * C_ * 2), dim3(256), 0, stream,
                     xpad, conv_w, conv_b, feats);
  hipLaunchKernelGGL(conv1_split, dim3(9 * B_ * HW_ / 256), dim3(256), 0, stream,
                     feats, box_w, box_b, obj_w, obj_b, tbox, scores);
  hipLaunchKernelGGL(radix_select, dim3(B_), dim3(1024), 0, stream,
                     scores, Kout, needEq, cnt, eqCnt);
  hipLaunchKernelGGL(compact_sel, dim3(B_ * 144), dim3(256), 0, stream,
                     scores, Kout, cnt, sel, eqCnt, eqList);
  hipLaunchKernelGGL(fix_eq, dim3(B_), dim3(256), 0, stream,
                     cnt, needEq, eqCnt, eqList, sel);
  hipLaunchKernelGGL(order_decode, dim3(B_), dim3(1024), 0, stream,
                     scores, sel, tbox, s2, b2);
  hipLaunchKernelGGL(mask_kernel, dim3(B_ * 63), dim3(256), 0, stream, b2, sup);
  hipLaunchKernelGGL(nms_out, dim3(B_), dim3(64), 0, stream, sup, b2, s2, out);
}

// Round 12
// 1187.423 us; speedup vs baseline: 1.6596x; 1.5200x over previous
//
#include <hip/hip_runtime.h>

#define B_ 8
#define C_ 256
#define H_ 64
#define W_ 64
#define HW_ 4096
#define A_ 9
#define SITES 36864      // A_*HW_
#define NPOST 1000
#define XCLIPF 4.1351666f   // (float)4.135166556742356
#define IMGF 1024.0f

__device__ inline unsigned keyf(float v) {
  unsigned u = __float_as_uint(v);
  return (u & 0x80000000u) ? ~u : (u | 0x80000000u);  // ascending uint == ascending float
}

// ---------------- K1: 3x3 conv + bias + relu, bit-exact f32, 2 rows/thread ----------------
// VERBATIM round-8 kernel (validated absmax 0.0, best measured conv: ~820us) except the
// blockIdx -> (b,co) mapping, now XCD-swizzled: b = blk&7 (== XCD under round-robin
// dispatch), co = blk>>3 ascending. All co-blocks of a batch land on one XCD and march
// through the same ci-stream together -> input stays hot in the 4MB per-XCD L2
// (r11 proved this swizzle cuts FETCH 140->61MB on the same data flow).
__global__ __launch_bounds__(256, 2) void conv3_strip(
    const float* __restrict__ x, const float* __restrict__ w,
    const float* __restrict__ bias, const float* __restrict__ zrow,
    float* __restrict__ feats) {
#pragma clang fp contract(off)
  int b  = blockIdx.x & 7;             // XCD-affine (perf-only; correctness independent)
  int co = blockIdx.x >> 3;
  int rih   = threadIdx.x >> 3;        // 0..31
  int chunk = threadIdx.x & 7;         // 0..7
  int r0 = rih << 1;                   // 0,2,...,62
  int c0 = chunk << 3;
  bool lef0 = (chunk == 0), rig0 = (chunk == 7);
  bool topz = (rih == 0), botz = (rih == 31);

  const float* xb = x + (size_t)b * C_ * HW_;
  const float* pT  = topz ? zrow : (xb + (ptrdiff_t)(r0 - 1) * W_ + c0);
  const float* pM0 = xb + (size_t)r0 * W_ + c0;
  const float* pM1 = xb + (size_t)(r0 + 1) * W_ + c0;
  const float* pB  = botz ? zrow : (xb + (size_t)(r0 + 2) * W_ + c0);
  ptrdiff_t sT = topz ? 0 : HW_;       // per-lane stride (floats)
  ptrdiff_t sB = botz ? 0 : HW_;
  const float* wp = w + (size_t)co * (C_ * 9);

  float acc0[8][9], acc1[8][9];
#pragma unroll
  for (int p = 0; p < 8; ++p)
#pragma unroll
    for (int t = 0; t < 9; ++t) { acc0[p][t] = 0.f; acc1[p][t] = 0.f; }

  for (int ci = 0; ci < C_; ++ci) {
    float4 tA  = ((const float4*)pT)[0],  tB4 = ((const float4*)pT)[1];
    float4 m0A = ((const float4*)pM0)[0], m0B = ((const float4*)pM0)[1];
    float4 m1A = ((const float4*)pM1)[0], m1B = ((const float4*)pM1)[1];
    float4 bA  = ((const float4*)pB)[0],  bB4 = ((const float4*)pB)[1];
    pT += sT; pM0 += HW_; pM1 += HW_; pB += sB;

    float T[10], M0[10], M1[10], Bo[10];
    T[1]=tA.x;  T[2]=tA.y;  T[3]=tA.z;  T[4]=tA.w;  T[5]=tB4.x;  T[6]=tB4.y;  T[7]=tB4.z;  T[8]=tB4.w;
    M0[1]=m0A.x; M0[2]=m0A.y; M0[3]=m0A.z; M0[4]=m0A.w; M0[5]=m0B.x; M0[6]=m0B.y; M0[7]=m0B.z; M0[8]=m0B.w;
    M1[1]=m1A.x; M1[2]=m1A.y; M1[3]=m1A.z; M1[4]=m1A.w; M1[5]=m1B.x; M1[6]=m1B.y; M1[7]=m1B.z; M1[8]=m1B.w;
    Bo[1]=bA.x; Bo[2]=bA.y; Bo[3]=bA.z; Bo[4]=bA.w; Bo[5]=bB4.x; Bo[6]=bB4.y; Bo[7]=bB4.z; Bo[8]=bB4.w;

    T[0]  = __shfl_up(T[8], 1u);    if (lef0) T[0]  = 0.f;
    T[9]  = __shfl_down(T[1], 1u);  if (rig0) T[9]  = 0.f;
    M0[0] = __shfl_up(M0[8], 1u);   if (lef0) M0[0] = 0.f;
    M0[9] = __shfl_down(M0[1], 1u); if (rig0) M0[9] = 0.f;
    M1[0] = __shfl_up(M1[8], 1u);   if (lef0) M1[0] = 0.f;
    M1[9] = __shfl_down(M1[1], 1u); if (rig0) M1[9] = 0.f;
    Bo[0] = __shfl_up(Bo[8], 1u);   if (lef0) Bo[0] = 0.f;
    Bo[9] = __shfl_down(Bo[1], 1u); if (rig0) Bo[9] = 0.f;

    float w9[9];
#pragma unroll
    for (int t = 0; t < 9; ++t) w9[t] = wp[ci * 9 + t];   // wave-uniform -> s_load

#pragma unroll
    for (int p = 0; p < 8; ++p) {
      acc0[p][0] = fmaf(w9[0], T[p],     acc0[p][0]);
      acc0[p][1] = fmaf(w9[1], T[p+1],   acc0[p][1]);
      acc0[p][2] = fmaf(w9[2], T[p+2],   acc0[p][2]);
      acc0[p][3] = fmaf(w9[3], M0[p],    acc0[p][3]);
      acc0[p][4] = fmaf(w9[4], M0[p+1],  acc0[p][4]);
      acc0[p][5] = fmaf(w9[5], M0[p+2],  acc0[p][5]);
      acc0[p][6] = fmaf(w9[6], M1[p],    acc0[p][6]);
      acc0[p][7] = fmaf(w9[7], M1[p+1],  acc0[p][7]);
      acc0[p][8] = fmaf(w9[8], M1[p+2],  acc0[p][8]);
      acc1[p][0] = fmaf(w9[0], M0[p],    acc1[p][0]);
      acc1[p][1] = fmaf(w9[1], M0[p+1],  acc1[p][1]);
      acc1[p][2] = fmaf(w9[2], M0[p+2],  acc1[p][2]);
      acc1[p][3] = fmaf(w9[3], M1[p],    acc1[p][3]);
      acc1[p][4] = fmaf(w9[4], M1[p+1],  acc1[p][4]);
      acc1[p][5] = fmaf(w9[5], M1[p+2],  acc1[p][5]);
      acc1[p][6] = fmaf(w9[6], Bo[p],    acc1[p][6]);
      acc1[p][7] = fmaf(w9[7], Bo[p+1],  acc1[p][7]);
      acc1[p][8] = fmaf(w9[8], Bo[p+2],  acc1[p][8]);
    }
  }

  float bv = bias[co];
  float ov0[8], ov1[8];
#pragma unroll
  for (int p = 0; p < 8; ++p) {
    float a = 0.f;
#pragma unroll
    for (int t = 0; t < 9; ++t) a = a + acc0[p][t];  // tap-ordered, left-assoc
    a = a + bv;
    ov0[p] = a > 0.f ? a : 0.f;
    float c = 0.f;
#pragma unroll
    for (int t = 0; t < 9; ++t) c = c + acc1[p][t];
    c = c + bv;
    ov1[p] = c > 0.f ? c : 0.f;
  }
  float* fbase = feats + ((size_t)b * C_ + co) * HW_;
  float4* fo0 = (float4*)(fbase + (size_t)r0 * W_ + c0);
  float4* fo1 = (float4*)(fbase + (size_t)(r0 + 1) * W_ + c0);
  fo0[0] = make_float4(ov0[0], ov0[1], ov0[2], ov0[3]);
  fo0[1] = make_float4(ov0[4], ov0[5], ov0[6], ov0[7]);
  fo1[0] = make_float4(ov1[0], ov1[1], ov1[2], ov1[3]);
  fo1[1] = make_float4(ov1[4], ov1[5], ov1[6], ov1[7]);
}

// ---------------- K2: 1x1 convs, 9-way channel split (5 chains/thread), bit-exact ----------------
__global__ __launch_bounds__(256) void conv1_split(
    const float* __restrict__ feats,
    const float* __restrict__ box_w, const float* __restrict__ box_b,
    const float* __restrict__ obj_w, const float* __restrict__ obj_b,
    float* __restrict__ tbox, float* __restrict__ scores) {
#pragma clang fp contract(off)
  int gidx = blockIdx.x * 256 + threadIdx.x;   // [0, 9*B_*HW_)
  int cgrp = gidx >> 15;                        // 0..8
  int rem  = gidx & 32767;
  int b  = rem >> 12;
  int hw = rem & 4095;
  int cbase = cgrp * 5;
  const float* f = feats + (size_t)b * C_ * HW_ + hw;
  const float* wrow[5];
#pragma unroll
  for (int jj = 0; jj < 5; ++jj) {
    int c = cbase + jj;
    wrow[jj] = (c < 36) ? (box_w + (size_t)c * C_) : (obj_w + (size_t)(c - 36) * C_);
  }
  float acc[5];
#pragma unroll
  for (int jj = 0; jj < 5; ++jj) acc[jj] = 0.f;
  for (int ci = 0; ci < C_; ++ci) {
    float fv = f[(size_t)ci * HW_];
#pragma unroll
    for (int jj = 0; jj < 5; ++jj)
      acc[jj] = fmaf(wrow[jj][ci], fv, acc[jj]);
  }
#pragma unroll
  for (int jj = 0; jj < 5; ++jj) {
    int c = cbase + jj;
    if (c < 36) {
      int k = c / 9, a = c - k * 9;
      tbox[(size_t)b * 4 * SITES + (size_t)k * SITES + (size_t)a * HW_ + hw] = acc[jj] + box_b[c];
    } else {
      int a = c - 36;
      scores[(size_t)b * SITES + (size_t)a * HW_ + hw] = acc[jj] + obj_b[a];
    }
  }
}

// ---------------- K3: exact radix-select of the 1000th-smallest key per batch ----------------
__global__ __launch_bounds__(1024) void radix_select(
    const float* __restrict__ scores, unsigned* __restrict__ Kout,
    int* __restrict__ needEq, int* __restrict__ cnt, int* __restrict__ eqCnt) {
  int b = blockIdx.x;
  const float* s = scores + (size_t)b * SITES;
  __shared__ unsigned hist[256];
  __shared__ unsigned sh_prefix, sh_mask, sh_cless;
  __shared__ int sh_target;
  if (threadIdx.x == 0) { sh_prefix = 0; sh_mask = 0; sh_target = NPOST - 1; sh_cless = 0; }
  for (int shift = 24; shift >= 0; shift -= 8) {
    if (threadIdx.x < 256) hist[threadIdx.x] = 0;
    __syncthreads();
    unsigned prefix = sh_prefix, mask = sh_mask;
    for (int i = threadIdx.x; i < SITES; i += 1024) {
      unsigned k = keyf(s[i]);
      if ((k & mask) == prefix) atomicAdd(&hist[(k >> shift) & 255u], 1u);
    }
    __syncthreads();
    if (threadIdx.x == 0) {
      unsigned cum = 0; int t = sh_target; int v = 0;
      for (; v < 256; ++v) {
        unsigned h = hist[v];
        if (cum + h > (unsigned)t) break;
        cum += h;
      }
      sh_prefix |= ((unsigned)v) << shift;
      sh_mask   |= 0xFFu << shift;
      sh_target  = t - (int)cum;
      sh_cless  += cum;
    }
    __syncthreads();
  }
  if (threadIdx.x == 0) {
    Kout[b] = sh_prefix;
    needEq[b] = NPOST - (int)sh_cless;
    cnt[b] = 0;
    eqCnt[b] = 0;
  }
}

// ---------------- K4: compact k<K sites; collect k==K sites ----------------
__global__ __launch_bounds__(256) void compact_sel(
    const float* __restrict__ scores, const unsigned* __restrict__ Kout,
    int* __restrict__ cnt, int* __restrict__ sel,
    int* __restrict__ eqCnt, int* __restrict__ eqList) {
  int b = blockIdx.x / 144;
  int i = (blockIdx.x % 144) * 256 + threadIdx.x;
  unsigned K = Kout[b];
  unsigned k = keyf(scores[(size_t)b * SITES + i]);
  if (k < K) {
    int pos = atomicAdd(&cnt[b], 1);
    sel[b * 1024 + pos] = i;               // arbitrary order: order_decode re-sorts
  } else if (k == K) {
    int e = atomicAdd(&eqCnt[b], 1);
    if (e < 4096) eqList[b * 4096 + e] = i;
  }
}

// ---------------- K4b: take the needEq smallest-index equal-key sites ----------------
__global__ __launch_bounds__(256) void fix_eq(
    const int* __restrict__ cnt, const int* __restrict__ needEq,
    const int* __restrict__ eqCnt, const int* __restrict__ eqList,
    int* __restrict__ sel) {
  int b = blockIdx.x;
  int E = eqCnt[b]; if (E > 4096) E = 4096;
  int need = needEq[b];
  int base = cnt[b];
  const int* el = eqList + b * 4096;
  for (int t = threadIdx.x; t < E; t += 256) {
    int site = el[t];
    int rank = 0;
    for (int q = 0; q < E; ++q) rank += (el[q] < site);
    if (rank < need) sel[b * 1024 + base + rank] = site;
  }
}

// ---------------- K5: descending order of the selected 1000 + fused decode ----------------
__global__ __launch_bounds__(1024) void order_decode(
    const float* __restrict__ scores, const int* __restrict__ sel,
    const float* __restrict__ tbox, float* __restrict__ s2, float* __restrict__ b2) {
#pragma clang fp contract(off)
  int b = blockIdx.x;
  int r = threadIdx.x;
  __shared__ float ss[NPOST];
  __shared__ int st[NPOST];
  if (r < NPOST) {
    int site = sel[b * 1024 + r];
    st[r] = site;
    ss[r] = scores[(size_t)b * SITES + site];
  }
  __syncthreads();
  if (r < NPOST) {
    float sr = ss[r]; int sir = st[r];
    int d = 0;
    for (int q = 0; q < NPOST; ++q) {
      float sq = ss[q];
      d += (int)((sq > sr) || (sq == sr && st[q] < sir));
    }
    s2[(size_t)b * NPOST + d] = sr;
    int site = sir;
    int a = site / HW_;
    int hw = site - a * HW_;
    int h = hw / W_, wc = hw - h * W_;
    int sidx = a / 3, ridx = a - sidx * 3;
    float scale = (sidx == 0) ? 128.f : ((sidx == 1) ? 256.f : 512.f);
    float ratio = (ridx == 0) ? 0.5f : ((ridx == 1) ? 1.0f : 2.0f);
    float sq = sqrtf(ratio);
    float wsa = scale / sq;
    float hsa = scale * sq;
    float cx = ((float)wc + 0.5f) * 16.f;
    float cy = ((float)h + 0.5f) * 16.f;
    float ax1 = cx - wsa * 0.5f;
    float ay1 = cy - hsa * 0.5f;
    float ax2 = cx + wsa * 0.5f;
    float ay2 = cy + hsa * 0.5f;
    float aw = ax2 - ax1, ah = ay2 - ay1;
    float m1 = 0.5f * aw, m2 = 0.5f * ah;
    float acx = ax1 + m1, acy = ay1 + m2;
    const float* tb = tbox + (size_t)b * 4 * SITES + site;
    float t0 = tb[0];
    float t1 = tb[SITES];
    float t2 = tb[2 * (size_t)SITES];
    float t3 = tb[3 * (size_t)SITES];
    if (t2 < -XCLIPF) t2 = -XCLIPF;
    if (t2 > XCLIPF) t2 = XCLIPF;
    if (t3 < -XCLIPF) t3 = -XCLIPF;
    if (t3 > XCLIPF) t3 = XCLIPF;
    float pm0 = t0 * aw;  float pcx = pm0 + acx;
    float pm1 = t1 * ah;  float pcy = pm1 + acy;
    float pw = expf(t2) * aw;
    float ph = expf(t3) * ah;
    float hw0 = 0.5f * pw, hh0 = 0.5f * ph;
    float x1 = pcx - hw0, y1 = pcy - hh0;
    float x2 = pcx + hw0, y2 = pcy + hh0;
    x1 = x1 < 0.f ? 0.f : (x1 > IMGF ? IMGF : x1);
    y1 = y1 < 0.f ? 0.f : (y1 > IMGF ? IMGF : y1);
    x2 = x2 < 0.f ? 0.f : (x2 > IMGF ? IMGF : x2);
    y2 = y2 < 0.f ? 0.f : (y2 > IMGF ? IMGF : y2);
    float* o = b2 + ((size_t)b * NPOST + d) * 4;
    o[0] = x1; o[1] = y1; o[2] = x2; o[3] = y2;
  }
}

// ---------------- K6a: suppression bitmask (j > i && IoU > 0.7), f32, exact op order ----------------
__global__ __launch_bounds__(256) void mask_kernel(
    const float* __restrict__ b2, unsigned long long* __restrict__ sup) {
#pragma clang fp contract(off)
  int b = blockIdx.x / 63;
  int i0 = (blockIdx.x % 63) * 16;
  __shared__ float bs[NPOST * 4];
  __shared__ float area[NPOST];
  for (int t = threadIdx.x; t < NPOST * 4; t += 256) bs[t] = b2[(size_t)b * NPOST * 4 + t];
  __syncthreads();
  for (int t = threadIdx.x; t < NPOST; t += 256)
    area[t] = (bs[t * 4 + 2] - bs[t * 4]) * (bs[t * 4 + 3] - bs[t * 4 + 1]);
  __syncthreads();
  int i = i0 + (threadIdx.x >> 4);
  int wd = threadIdx.x & 15;
  if (i >= NPOST) return;
  float ax1 = bs[i * 4], ay1 = bs[i * 4 + 1], ax2 = bs[i * 4 + 2], ay2 = bs[i * 4 + 3];
  float aa = area[i];
  unsigned long long m = 0;
  for (int bit = 0; bit < 64; ++bit) {
    int j = wd * 64 + bit;
    if (j > i && j < NPOST) {
      float lx = fmaxf(ax1, bs[j * 4]);
      float ly = fmaxf(ay1, bs[j * 4 + 1]);
      float rx = fminf(ax2, bs[j * 4 + 2]);
      float ry = fminf(ay2, bs[j * 4 + 3]);
      float iw = rx - lx; if (iw < 0.f) iw = 0.f;
      float ih = ry - ly; if (ih < 0.f) ih = 0.f;
      float inter = iw * ih;
      float denom = (aa + area[j]) - inter;
      float iou = inter / denom;
      if (iou > 0.7f) m |= 1ull << bit;
    }
  }
  sup[((size_t)b * NPOST + i) * 16 + wd] = m;
}

// ---------------- K6b: wave-synchronous NMS scan + compaction + zero fill ----------------
__global__ __launch_bounds__(64) void nms_out(
    const unsigned long long* __restrict__ sup, const float* __restrict__ b2,
    const float* __restrict__ s2, float* __restrict__ out) {
  int b = blockIdx.x;
  int lane = threadIdx.x;
  unsigned long long kw = 0;
  if (lane < 16) kw = (lane < 15) ? ~0ull : ((1ull << 40) - 1);  // bits 960..999 valid
  const unsigned long long* ms = sup + (size_t)b * NPOST * 16;
  unsigned long long m_cur = (lane < 16) ? ms[lane] : 0ull;
  for (int i = 0; i < NPOST; ++i) {
    unsigned long long m_nxt = (i + 1 < NPOST && lane < 16) ? ms[(size_t)(i + 1) * 16 + lane] : 0ull;
    unsigned long long w = __shfl(kw, i >> 6, 64);
    if ((w >> (i & 63)) & 1ull) {
      if (lane < 16) kw &= ~m_cur;
    }
    m_cur = m_nxt;
  }
  __shared__ unsigned long long keeps[16];
  if (lane < 16) keeps[lane] = kw;
  __syncthreads();
  int total = 0;
#pragma unroll
  for (int k = 0; k < 16; ++k) total += __popcll(keeps[k]);
  for (int i = lane; i < NPOST; i += 64) {
    int w = i >> 6;
    int before = 0;
    for (int k = 0; k < w; ++k) before += __popcll(keeps[k]);
    before += __popcll(keeps[w] & ((1ull << (i & 63)) - 1));
    bool kept = (keeps[w] >> (i & 63)) & 1ull;
    if (kept) {
      size_t ob = (size_t)b * (NPOST * 5) + (size_t)before * 5;
      const float* src = b2 + ((size_t)b * NPOST + i) * 4;
      out[ob + 0] = src[0];
      out[ob + 1] = src[1];
      out[ob + 2] = src[2];
      out[ob + 3] = src[3];
      out[ob + 4] = s2[(size_t)b * NPOST + i];
    }
    if (i >= total) {
      size_t ob = (size_t)b * (NPOST * 5) + (size_t)i * 5;
      for (int c = 0; c < 5; ++c) out[ob + c] = 0.f;
    }
  }
}

extern "C" void kernel_launch(void* const* d_in, const int* in_sizes, int n_in,
                              void* d_out, int out_size, void* d_ws, size_t ws_size,
                              hipStream_t stream) {
  const float *x = nullptr, *conv_w = nullptr, *conv_b = nullptr,
              *box_w = nullptr, *box_b = nullptr, *obj_w = nullptr, *obj_b = nullptr;
  for (int i = 0; i < n_in; ++i) {
    switch (in_sizes[i]) {
      case 8388608: x = (const float*)d_in[i]; break;
      case 589824:  conv_w = (const float*)d_in[i]; break;
      case 256:     conv_b = (const float*)d_in[i]; break;
      case 9216:    box_w = (const float*)d_in[i]; break;
      case 36:      box_b = (const float*)d_in[i]; break;
      case 2304:    obj_w = (const float*)d_in[i]; break;
      case 9:       obj_b = (const float*)d_in[i]; break;
    }
  }
  float* out = (float*)d_out;

  char* p = (char*)d_ws;
  auto alloc = [&](size_t n) { char* q = p; p += (n + 255) & ~255ull; return (void*)q; };
  float* feats  = (float*)alloc((size_t)B_ * C_ * HW_ * 4);       // 33.55 MB
  float* tbox   = (float*)alloc((size_t)B_ * 4 * SITES * 4);      // 4.72 MB
  float* scores = (float*)alloc((size_t)B_ * SITES * 4);          // 1.18 MB
  float* zrow   = (float*)alloc(256);                              // zero halo row
  unsigned* Kout = (unsigned*)alloc(B_ * 4);
  int* needEq    = (int*)alloc(B_ * 4);
  int* cnt       = (int*)alloc(B_ * 4);
  int* eqCnt     = (int*)alloc(B_ * 4);
  int* eqList    = (int*)alloc((size_t)B_ * 4096 * 4);
  int* sel       = (int*)alloc((size_t)B_ * 1024 * 4);
  float* s2      = (float*)alloc((size_t)B_ * NPOST * 4);
  float* b2      = (float*)alloc((size_t)B_ * NPOST * 4 * 4);
  unsigned long long* sup = (unsigned long long*)alloc((size_t)B_ * NPOST * 16 * 8); // 1.02 MB

  hipMemsetAsync(zrow, 0, 256, stream);
  hipLaunchKernelGGL(conv3_strip, dim3(B_ * C_), dim3(256), 0, stream,
                     x, conv_w, conv_b, zrow, feats);
  hipLaunchKernelGGL(conv1_split, dim3(9 * B_ * HW_ / 256), dim3(256), 0, stream,
                     feats, box_w, box_b, obj_w, obj_b, tbox, scores);
  hipLaunchKernelGGL(radix_select, dim3(B_), dim3(1024), 0, stream,
                     scores, Kout, needEq, cnt, eqCnt);
  hipLaunchKernelGGL(compact_sel, dim3(B_ * 144), dim3(256), 0, stream,
                     scores, Kout, cnt, sel, eqCnt, eqList);
  hipLaunchKernelGGL(fix_eq, dim3(B_), dim3(256), 0, stream,
                     cnt, needEq, eqCnt, eqList, sel);
  hipLaunchKernelGGL(order_decode, dim3(B_), dim3(1024), 0, stream,
                     scores, sel, tbox, s2, b2);
  hipLaunchKernelGGL(mask_kernel, dim3(B_ * 63), dim3(256), 0, stream, b2, sup);
  hipLaunchKernelGGL(nms_out, dim3(B_), dim3(64), 0, stream, sup, b2, s2, out);
}

// Round 13
// 1169.208 us; speedup vs baseline: 1.6855x; 1.0156x over previous
//
#include <hip/hip_runtime.h>

#define B_ 8
#define C_ 256
#define H_ 64
#define W_ 64
#define HW_ 4096
#define A_ 9
#define SITES 36864      // A_*HW_
#define NPOST 1000
#define XCLIPF 4.1351666f   // (float)4.135166556742356
#define IMGF 1024.0f

__device__ inline unsigned keyf(float v) {
  unsigned u = __float_as_uint(v);
  return (u & 0x80000000u) ? ~u : (u | 0x80000000u);  // ascending uint == ascending float
}

// ---------------- K1: 3x3 conv + bias + relu, bit-exact f32, 2 rows/thread ----------------
// VERBATIM round-12 kernel (validated absmax 0.0, best measured conv ~795us; XCD swizzle).
__global__ __launch_bounds__(256, 2) void conv3_strip(
    const float* __restrict__ x, const float* __restrict__ w,
    const float* __restrict__ bias, const float* __restrict__ zrow,
    float* __restrict__ feats) {
#pragma clang fp contract(off)
  int b  = blockIdx.x & 7;             // XCD-affine (perf-only; correctness independent)
  int co = blockIdx.x >> 3;
  int rih   = threadIdx.x >> 3;        // 0..31
  int chunk = threadIdx.x & 7;         // 0..7
  int r0 = rih << 1;                   // 0,2,...,62
  int c0 = chunk << 3;
  bool lef0 = (chunk == 0), rig0 = (chunk == 7);
  bool topz = (rih == 0), botz = (rih == 31);

  const float* xb = x + (size_t)b * C_ * HW_;
  const float* pT  = topz ? zrow : (xb + (ptrdiff_t)(r0 - 1) * W_ + c0);
  const float* pM0 = xb + (size_t)r0 * W_ + c0;
  const float* pM1 = xb + (size_t)(r0 + 1) * W_ + c0;
  const float* pB  = botz ? zrow : (xb + (size_t)(r0 + 2) * W_ + c0);
  ptrdiff_t sT = topz ? 0 : HW_;       // per-lane stride (floats)
  ptrdiff_t sB = botz ? 0 : HW_;
  const float* wp = w + (size_t)co * (C_ * 9);

  float acc0[8][9], acc1[8][9];
#pragma unroll
  for (int p = 0; p < 8; ++p)
#pragma unroll
    for (int t = 0; t < 9; ++t) { acc0[p][t] = 0.f; acc1[p][t] = 0.f; }

  for (int ci = 0; ci < C_; ++ci) {
    float4 tA  = ((const float4*)pT)[0],  tB4 = ((const float4*)pT)[1];
    float4 m0A = ((const float4*)pM0)[0], m0B = ((const float4*)pM0)[1];
    float4 m1A = ((const float4*)pM1)[0], m1B = ((const float4*)pM1)[1];
    float4 bA  = ((const float4*)pB)[0],  bB4 = ((const float4*)pB)[1];
    pT += sT; pM0 += HW_; pM1 += HW_; pB += sB;

    float T[10], M0[10], M1[10], Bo[10];
    T[1]=tA.x;  T[2]=tA.y;  T[3]=tA.z;  T[4]=tA.w;  T[5]=tB4.x;  T[6]=tB4.y;  T[7]=tB4.z;  T[8]=tB4.w;
    M0[1]=m0A.x; M0[2]=m0A.y; M0[3]=m0A.z; M0[4]=m0A.w; M0[5]=m0B.x; M0[6]=m0B.y; M0[7]=m0B.z; M0[8]=m0B.w;
    M1[1]=m1A.x; M1[2]=m1A.y; M1[3]=m1A.z; M1[4]=m1A.w; M1[5]=m1B.x; M1[6]=m1B.y; M1[7]=m1B.z; M1[8]=m1B.w;
    Bo[1]=bA.x; Bo[2]=bA.y; Bo[3]=bA.z; Bo[4]=bA.w; Bo[5]=bB4.x; Bo[6]=bB4.y; Bo[7]=bB4.z; Bo[8]=bB4.w;

    T[0]  = __shfl_up(T[8], 1u);    if (lef0) T[0]  = 0.f;
    T[9]  = __shfl_down(T[1], 1u);  if (rig0) T[9]  = 0.f;
    M0[0] = __shfl_up(M0[8], 1u);   if (lef0) M0[0] = 0.f;
    M0[9] = __shfl_down(M0[1], 1u); if (rig0) M0[9] = 0.f;
    M1[0] = __shfl_up(M1[8], 1u);   if (lef0) M1[0] = 0.f;
    M1[9] = __shfl_down(M1[1], 1u); if (rig0) M1[9] = 0.f;
    Bo[0] = __shfl_up(Bo[8], 1u);   if (lef0) Bo[0] = 0.f;
    Bo[9] = __shfl_down(Bo[1], 1u); if (rig0) Bo[9] = 0.f;

    float w9[9];
#pragma unroll
    for (int t = 0; t < 9; ++t) w9[t] = wp[ci * 9 + t];   // wave-uniform -> s_load

#pragma unroll
    for (int p = 0; p < 8; ++p) {
      acc0[p][0] = fmaf(w9[0], T[p],     acc0[p][0]);
      acc0[p][1] = fmaf(w9[1], T[p+1],   acc0[p][1]);
      acc0[p][2] = fmaf(w9[2], T[p+2],   acc0[p][2]);
      acc0[p][3] = fmaf(w9[3], M0[p],    acc0[p][3]);
      acc0[p][4] = fmaf(w9[4], M0[p+1],  acc0[p][4]);
      acc0[p][5] = fmaf(w9[5], M0[p+2],  acc0[p][5]);
      acc0[p][6] = fmaf(w9[6], M1[p],    acc0[p][6]);
      acc0[p][7] = fmaf(w9[7], M1[p+1],  acc0[p][7]);
      acc0[p][8] = fmaf(w9[8], M1[p+2],  acc0[p][8]);
      acc1[p][0] = fmaf(w9[0], M0[p],    acc1[p][0]);
      acc1[p][1] = fmaf(w9[1], M0[p+1],  acc1[p][1]);
      acc1[p][2] = fmaf(w9[2], M0[p+2],  acc1[p][2]);
      acc1[p][3] = fmaf(w9[3], M1[p],    acc1[p][3]);
      acc1[p][4] = fmaf(w9[4], M1[p+1],  acc1[p][4]);
      acc1[p][5] = fmaf(w9[5], M1[p+2],  acc1[p][5]);
      acc1[p][6] = fmaf(w9[6], Bo[p],    acc1[p][6]);
      acc1[p][7] = fmaf(w9[7], Bo[p+1],  acc1[p][7]);
      acc1[p][8] = fmaf(w9[8], Bo[p+2],  acc1[p][8]);
    }
  }

  float bv = bias[co];
  float ov0[8], ov1[8];
#pragma unroll
  for (int p = 0; p < 8; ++p) {
    float a = 0.f;
#pragma unroll
    for (int t = 0; t < 9; ++t) a = a + acc0[p][t];  // tap-ordered, left-assoc
    a = a + bv;
    ov0[p] = a > 0.f ? a : 0.f;
    float c = 0.f;
#pragma unroll
    for (int t = 0; t < 9; ++t) c = c + acc1[p][t];
    c = c + bv;
    ov1[p] = c > 0.f ? c : 0.f;
  }
  float* fbase = feats + ((size_t)b * C_ + co) * HW_;
  float4* fo0 = (float4*)(fbase + (size_t)r0 * W_ + c0);
  float4* fo1 = (float4*)(fbase + (size_t)(r0 + 1) * W_ + c0);
  fo0[0] = make_float4(ov0[0], ov0[1], ov0[2], ov0[3]);
  fo0[1] = make_float4(ov0[4], ov0[5], ov0[6], ov0[7]);
  fo1[0] = make_float4(ov1[0], ov1[1], ov1[2], ov1[3]);
  fo1[1] = make_float4(ov1[4], ov1[5], ov1[6], ov1[7]);
}

// ---------------- K2: 1x1 convs, 3-way channel split (15 chains/thread), bit-exact ----------------
// feats read 3x (was 9x = 302MB -> 100MB). Each channel's fmaf chain over ci ascending
// is verbatim the validated order.
__global__ __launch_bounds__(256) void conv1_split3(
    const float* __restrict__ feats,
    const float* __restrict__ box_w, const float* __restrict__ box_b,
    const float* __restrict__ obj_w, const float* __restrict__ obj_b,
    float* __restrict__ tbox, float* __restrict__ scores) {
#pragma clang fp contract(off)
  int gidx = blockIdx.x * 256 + threadIdx.x;   // [0, 3*B_*HW_)
  int cgrp = gidx >> 15;                        // 0..2
  int rem  = gidx & 32767;
  int b  = rem >> 12;
  int hw = rem & 4095;
  int cbase = cgrp * 15;
  const float* f = feats + (size_t)b * C_ * HW_ + hw;
  const float* wrow[15];
#pragma unroll
  for (int jj = 0; jj < 15; ++jj) {
    int c = cbase + jj;
    wrow[jj] = (c < 36) ? (box_w + (size_t)c * C_) : (obj_w + (size_t)(c - 36) * C_);
  }
  float acc[15];
#pragma unroll
  for (int jj = 0; jj < 15; ++jj) acc[jj] = 0.f;
  for (int ci = 0; ci < C_; ++ci) {
    float fv = f[(size_t)ci * HW_];
#pragma unroll
    for (int jj = 0; jj < 15; ++jj)
      acc[jj] = fmaf(wrow[jj][ci], fv, acc[jj]);
  }
#pragma unroll
  for (int jj = 0; jj < 15; ++jj) {
    int c = cbase + jj;
    if (c < 36) {
      int k = c / 9, a = c - k * 9;
      tbox[(size_t)b * 4 * SITES + (size_t)k * SITES + (size_t)a * HW_ + hw] = acc[jj] + box_b[c];
    } else {
      int a = c - 36;
      scores[(size_t)b * SITES + (size_t)a * HW_ + hw] = acc[jj] + obj_b[a];
    }
  }
}

// ---------------- K3: exact radix-select of the 1000th-smallest key per batch ----------------
__global__ __launch_bounds__(1024) void radix_select(
    const float* __restrict__ scores, unsigned* __restrict__ Kout,
    int* __restrict__ needEq, int* __restrict__ cnt, int* __restrict__ eqCnt) {
  int b = blockIdx.x;
  const float* s = scores + (size_t)b * SITES;
  __shared__ unsigned hist[256];
  __shared__ unsigned sh_prefix, sh_mask, sh_cless;
  __shared__ int sh_target;
  if (threadIdx.x == 0) { sh_prefix = 0; sh_mask = 0; sh_target = NPOST - 1; sh_cless = 0; }
  for (int shift = 24; shift >= 0; shift -= 8) {
    if (threadIdx.x < 256) hist[threadIdx.x] = 0;
    __syncthreads();
    unsigned prefix = sh_prefix, mask = sh_mask;
    for (int i = threadIdx.x; i < SITES; i += 1024) {
      unsigned k = keyf(s[i]);
      if ((k & mask) == prefix) atomicAdd(&hist[(k >> shift) & 255u], 1u);
    }
    __syncthreads();
    if (threadIdx.x == 0) {
      unsigned cum = 0; int t = sh_target; int v = 0;
      for (; v < 256; ++v) {
        unsigned h = hist[v];
        if (cum + h > (unsigned)t) break;
        cum += h;
      }
      sh_prefix |= ((unsigned)v) << shift;
      sh_mask   |= 0xFFu << shift;
      sh_target  = t - (int)cum;
      sh_cless  += cum;
    }
    __syncthreads();
  }
  if (threadIdx.x == 0) {
    Kout[b] = sh_prefix;
    needEq[b] = NPOST - (int)sh_cless;
    cnt[b] = 0;
    eqCnt[b] = 0;
  }
}

// ---------------- K4: compact k<K sites; collect k==K sites ----------------
__global__ __launch_bounds__(256) void compact_sel(
    const float* __restrict__ scores, const unsigned* __restrict__ Kout,
    int* __restrict__ cnt, int* __restrict__ sel,
    int* __restrict__ eqCnt, int* __restrict__ eqList) {
  int b = blockIdx.x / 144;
  int i = (blockIdx.x % 144) * 256 + threadIdx.x;
  unsigned K = Kout[b];
  unsigned k = keyf(scores[(size_t)b * SITES + i]);
  if (k < K) {
    int pos = atomicAdd(&cnt[b], 1);
    sel[b * 1024 + pos] = i;               // arbitrary order: order_decode re-sorts
  } else if (k == K) {
    int e = atomicAdd(&eqCnt[b], 1);
    if (e < 4096) eqList[b * 4096 + e] = i;
  }
}

// ---------------- K4b: take the needEq smallest-index equal-key sites ----------------
__global__ __launch_bounds__(256) void fix_eq(
    const int* __restrict__ cnt, const int* __restrict__ needEq,
    const int* __restrict__ eqCnt, const int* __restrict__ eqList,
    int* __restrict__ sel) {
  int b = blockIdx.x;
  int E = eqCnt[b]; if (E > 4096) E = 4096;
  int need = needEq[b];
  int base = cnt[b];
  const int* el = eqList + b * 4096;
  for (int t = threadIdx.x; t < E; t += 256) {
    int site = el[t];
    int rank = 0;
    for (int q = 0; q < E; ++q) rank += (el[q] < site);
    if (rank < need) sel[b * 1024 + base + rank] = site;
  }
}

// ---------------- K5: descending order + fused decode, 8 blocks/batch (125 ranks each) ----------------
// Per-r computation identical to the validated order_decode; only the r-partition changed.
__global__ __launch_bounds__(128) void order_decode(
    const float* __restrict__ scores, const int* __restrict__ sel,
    const float* __restrict__ tbox, float* __restrict__ s2, float* __restrict__ b2) {
#pragma clang fp contract(off)
  int b   = blockIdx.x >> 3;
  int r   = ((blockIdx.x & 7) * 125) + threadIdx.x;   // 125 ranks per block
  __shared__ float ss[NPOST];
  __shared__ int st[NPOST];
  for (int t = threadIdx.x; t < NPOST; t += 128) {
    int site = sel[b * 1024 + t];
    st[t] = site;
    ss[t] = scores[(size_t)b * SITES + site];
  }
  __syncthreads();
  if (threadIdx.x < 125) {
    float sr = ss[r]; int sir = st[r];
    int d = 0;
    for (int q = 0; q < NPOST; ++q) {
      float sq = ss[q];
      d += (int)((sq > sr) || (sq == sr && st[q] < sir));
    }
    s2[(size_t)b * NPOST + d] = sr;
    int site = sir;
    int a = site / HW_;
    int hw = site - a * HW_;
    int h = hw / W_, wc = hw - h * W_;
    int sidx = a / 3, ridx = a - sidx * 3;
    float scale = (sidx == 0) ? 128.f : ((sidx == 1) ? 256.f : 512.f);
    float ratio = (ridx == 0) ? 0.5f : ((ridx == 1) ? 1.0f : 2.0f);
    float sq = sqrtf(ratio);
    float wsa = scale / sq;
    float hsa = scale * sq;
    float cx = ((float)wc + 0.5f) * 16.f;
    float cy = ((float)h + 0.5f) * 16.f;
    float ax1 = cx - wsa * 0.5f;
    float ay1 = cy - hsa * 0.5f;
    float ax2 = cx + wsa * 0.5f;
    float ay2 = cy + hsa * 0.5f;
    float aw = ax2 - ax1, ah = ay2 - ay1;
    float m1 = 0.5f * aw, m2 = 0.5f * ah;
    float acx = ax1 + m1, acy = ay1 + m2;
    const float* tb = tbox + (size_t)b * 4 * SITES + site;
    float t0 = tb[0];
    float t1 = tb[SITES];
    float t2 = tb[2 * (size_t)SITES];
    float t3 = tb[3 * (size_t)SITES];
    if (t2 < -XCLIPF) t2 = -XCLIPF;
    if (t2 > XCLIPF) t2 = XCLIPF;
    if (t3 < -XCLIPF) t3 = -XCLIPF;
    if (t3 > XCLIPF) t3 = XCLIPF;
    float pm0 = t0 * aw;  float pcx = pm0 + acx;
    float pm1 = t1 * ah;  float pcy = pm1 + acy;
    float pw = expf(t2) * aw;
    float ph = expf(t3) * ah;
    float hw0 = 0.5f * pw, hh0 = 0.5f * ph;
    float x1 = pcx - hw0, y1 = pcy - hh0;
    float x2 = pcx + hw0, y2 = pcy + hh0;
    x1 = x1 < 0.f ? 0.f : (x1 > IMGF ? IMGF : x1);
    y1 = y1 < 0.f ? 0.f : (y1 > IMGF ? IMGF : y1);
    x2 = x2 < 0.f ? 0.f : (x2 > IMGF ? IMGF : x2);
    y2 = y2 < 0.f ? 0.f : (y2 > IMGF ? IMGF : y2);
    float* o = b2 + ((size_t)b * NPOST + d) * 4;
    o[0] = x1; o[1] = y1; o[2] = x2; o[3] = y2;
  }
}

// ---------------- K6a: suppression bitmask, f32 exact op order; bank-conflict-fixed mapping ----
// Thread mapping swapped: i = i0 + (tid&15), wd = tid>>4 -> 4 distinct j per wave
// (4-way LDS conflict, ~free) instead of 16 distinct j on one bank (16-way).
__global__ __launch_bounds__(256) void mask_kernel(
    const float* __restrict__ b2, unsigned long long* __restrict__ sup) {
#pragma clang fp contract(off)
  int b = blockIdx.x / 63;
  int i0 = (blockIdx.x % 63) * 16;
  __shared__ float bs[NPOST * 4];
  __shared__ float area[NPOST];
  for (int t = threadIdx.x; t < NPOST * 4; t += 256) bs[t] = b2[(size_t)b * NPOST * 4 + t];
  __syncthreads();
  for (int t = threadIdx.x; t < NPOST; t += 256)
    area[t] = (bs[t * 4 + 2] - bs[t * 4]) * (bs[t * 4 + 3] - bs[t * 4 + 1]);
  __syncthreads();
  int i = i0 + (threadIdx.x & 15);
  int wd = threadIdx.x >> 4;
  if (i >= NPOST) return;
  float ax1 = bs[i * 4], ay1 = bs[i * 4 + 1], ax2 = bs[i * 4 + 2], ay2 = bs[i * 4 + 3];
  float aa = area[i];
  unsigned long long m = 0;
  for (int bit = 0; bit < 64; ++bit) {
    int j = wd * 64 + bit;
    if (j > i && j < NPOST) {
      float lx = fmaxf(ax1, bs[j * 4]);
      float ly = fmaxf(ay1, bs[j * 4 + 1]);
      float rx = fminf(ax2, bs[j * 4 + 2]);
      float ry = fminf(ay2, bs[j * 4 + 3]);
      float iw = rx - lx; if (iw < 0.f) iw = 0.f;
      float ih = ry - ly; if (ih < 0.f) ih = 0.f;
      float inter = iw * ih;
      float denom = (aa + area[j]) - inter;
      float iou = inter / denom;
      if (iou > 0.7f) m |= 1ull << bit;
    }
  }
  sup[((size_t)b * NPOST + i) * 16 + wd] = m;
}

// ---------------- K6b: wave-synchronous NMS scan, 8-deep prefetch + compaction ----------------
__global__ __launch_bounds__(64) void nms_out(
    const unsigned long long* __restrict__ sup, const float* __restrict__ b2,
    const float* __restrict__ s2, float* __restrict__ out) {
  int b = blockIdx.x;
  int lane = threadIdx.x;
  unsigned long long kw = 0;
  if (lane < 16) kw = (lane < 15) ? ~0ull : ((1ull << 40) - 1);  // bits 960..999 valid
  const unsigned long long* ms = sup + (size_t)b * NPOST * 16;
  unsigned long long mb[8];
#pragma unroll
  for (int k = 0; k < 8; ++k)
    mb[k] = (lane < 16) ? ms[(size_t)k * 16 + lane] : 0ull;
  for (int i0 = 0; i0 < NPOST; i0 += 8) {          // 1000 = 8*125
    unsigned long long nb[8];
#pragma unroll
    for (int k = 0; k < 8; ++k) {
      int nx = i0 + 8 + k;
      nb[k] = (nx < NPOST && lane < 16) ? ms[(size_t)nx * 16 + lane] : 0ull;
    }
#pragma unroll
    for (int k = 0; k < 8; ++k) {
      int i = i0 + k;
      unsigned long long w = __shfl(kw, i >> 6, 64);  // broadcast word holding bit i
      if ((w >> (i & 63)) & 1ull) {                   // wave-uniform branch
        if (lane < 16) kw &= ~mb[k];                  // bit i never set in row i (j>i only)
      }
    }
#pragma unroll
    for (int k = 0; k < 8; ++k) mb[k] = nb[k];
  }
  __shared__ unsigned long long keeps[16];
  if (lane < 16) keeps[lane] = kw;
  __syncthreads();
  int total = 0;
#pragma unroll
  for (int k = 0; k < 16; ++k) total += __popcll(keeps[k]);
  for (int i = lane; i < NPOST; i += 64) {
    int w = i >> 6;
    int before = 0;
    for (int k = 0; k < w; ++k) before += __popcll(keeps[k]);
    before += __popcll(keeps[w] & ((1ull << (i & 63)) - 1));
    bool kept = (keeps[w] >> (i & 63)) & 1ull;
    if (kept) {
      size_t ob = (size_t)b * (NPOST * 5) + (size_t)before * 5;
      const float* src = b2 + ((size_t)b * NPOST + i) * 4;
      out[ob + 0] = src[0];
      out[ob + 1] = src[1];
      out[ob + 2] = src[2];
      out[ob + 3] = src[3];
      out[ob + 4] = s2[(size_t)b * NPOST + i];
    }
    if (i >= total) {
      size_t ob = (size_t)b * (NPOST * 5) + (size_t)i * 5;
      for (int c = 0; c < 5; ++c) out[ob + c] = 0.f;
    }
  }
}

extern "C" void kernel_launch(void* const* d_in, const int* in_sizes, int n_in,
                              void* d_out, int out_size, void* d_ws, size_t ws_size,
                              hipStream_t stream) {
  const float *x = nullptr, *conv_w = nullptr, *conv_b = nullptr,
              *box_w = nullptr, *box_b = nullptr, *obj_w = nullptr, *obj_b = nullptr;
  for (int i = 0; i < n_in; ++i) {
    switch (in_sizes[i]) {
      case 8388608: x = (const float*)d_in[i]; break;
      case 589824:  conv_w = (const float*)d_in[i]; break;
      case 256:     conv_b = (const float*)d_in[i]; break;
      case 9216:    box_w = (const float*)d_in[i]; break;
      case 36:      box_b = (const float*)d_in[i]; break;
      case 2304:    obj_w = (const float*)d_in[i]; break;
      case 9:       obj_b = (const float*)d_in[i]; break;
    }
  }
  float* out = (float*)d_out;

  char* p = (char*)d_ws;
  auto alloc = [&](size_t n) { char* q = p; p += (n + 255) & ~255ull; return (void*)q; };
  float* feats  = (float*)alloc((size_t)B_ * C_ * HW_ * 4);       // 33.55 MB
  float* tbox   = (float*)alloc((size_t)B_ * 4 * SITES * 4);      // 4.72 MB
  float* scores = (float*)alloc((size_t)B_ * SITES * 4);          // 1.18 MB
  float* zrow   = (float*)alloc(256);                              // zero halo row
  unsigned* Kout = (unsigned*)alloc(B_ * 4);
  int* needEq    = (int*)alloc(B_ * 4);
  int* cnt       = (int*)alloc(B_ * 4);
  int* eqCnt     = (int*)alloc(B_ * 4);
  int* eqList    = (int*)alloc((size_t)B_ * 4096 * 4);
  int* sel       = (int*)alloc((size_t)B_ * 1024 * 4);
  float* s2      = (float*)alloc((size_t)B_ * NPOST * 4);
  float* b2      = (float*)alloc((size_t)B_ * NPOST * 4 * 4);
  unsigned long long* sup = (unsigned long long*)alloc((size_t)B_ * NPOST * 16 * 8); // 1.02 MB

  hipMemsetAsync(zrow, 0, 256, stream);
  hipLaunchKernelGGL(conv3_strip, dim3(B_ * C_), dim3(256), 0, stream,
                     x, conv_w, conv_b, zrow, feats);
  hipLaunchKernelGGL(conv1_split3, dim3(3 * B_ * HW_ / 256), dim3(256), 0, stream,
                     feats, box_w, box_b, obj_w, obj_b, tbox, scores);
  hipLaunchKernelGGL(radix_select, dim3(B_), dim3(1024), 0, stream,
                     scores, Kout, needEq, cnt, eqCnt);
  hipLaunchKernelGGL(compact_sel, dim3(B_ * 144), dim3(256), 0, stream,
                     scores, Kout, cnt, sel, eqCnt, eqList);
  hipLaunchKernelGGL(fix_eq, dim3(B_), dim3(256), 0, stream,
                     cnt, needEq, eqCnt, eqList, sel);
  hipLaunchKernelGGL(order_decode, dim3(B_ * 8), dim3(128), 0, stream,
                     scores, sel, tbox, s2, b2);
  hipLaunchKernelGGL(mask_kernel, dim3(B_ * 63), dim3(256), 0, stream, b2, sup);
  hipLaunchKernelGGL(nms_out, dim3(B_), dim3(64), 0, stream, sup, b2, s2, out);
}

// Round 14
// 1086.104 us; speedup vs baseline: 1.8144x; 1.0765x over previous
//
#include <hip/hip_runtime.h>

#define B_ 8
#define C_ 256
#define H_ 64
#define W_ 64
#define HW_ 4096
#define A_ 9
#define SITES 36864      // A_*HW_
#define NPOST 1000
#define XCLIPF 4.1351666f   // (float)4.135166556742356
#define IMGF 1024.0f

__device__ inline unsigned keyf(float v) {
  unsigned u = __float_as_uint(v);
  return (u & 0x80000000u) ? ~u : (u | 0x80000000u);  // ascending uint == ascending float
}

// ---------------- K1: 3x3 conv + bias + relu, bit-exact f32, 1 row x 2 co per thread ----------
// Same validated shfl-strip family (the only structure that pipelines: r7/r12/r13).
// One 3-row window (zrow stride-0 vertical halo, shfl horizontal halo) feeds TWO output
// channels -> x-stream read by 128 blocks/batch instead of 256 (FETCH halves), FMA issue
// fraction rises to ~85%. Each (co,px,tap) fmaf chain over ci ascending and the
// tap-ordered left-assoc epilogue are verbatim the validated r7/r13 code. absmax 0.0 family.
// grid: B_*(C_/2)*2 = 2048 blocks, XCD swizzle b=blk&7; 256 threads; 8 px/thread.
__global__ __launch_bounds__(256, 2) void conv3_2co(
    const float* __restrict__ x, const float* __restrict__ w,
    const float* __restrict__ bias, const float* __restrict__ zrow,
    float* __restrict__ feats) {
#pragma clang fp contract(off)
  int b   = blockIdx.x & 7;            // XCD-affine (perf-only)
  int j   = blockIdx.x >> 3;           // 0..255
  int cop  = j & 127;                  // co-pair
  int half = j >> 7;                   // 0/1
  int co0 = cop << 1, co1 = co0 + 1;
  int rih   = threadIdx.x >> 3;        // 0..31
  int chunk = threadIdx.x & 7;         // 0..7
  int gr = (half << 5) + rih;          // output row 0..63
  int c0 = chunk << 3;
  bool lef0 = (chunk == 0), rig0 = (chunk == 7);
  bool topz = (gr == 0), botz = (gr == 63);

  const float* xb = x + (size_t)b * C_ * HW_;
  const float* pT = topz ? zrow : (xb + (ptrdiff_t)(gr - 1) * W_ + c0);
  const float* pM = xb + (size_t)gr * W_ + c0;
  const float* pB = botz ? zrow : (xb + (size_t)(gr + 1) * W_ + c0);
  ptrdiff_t sT = topz ? 0 : HW_;
  ptrdiff_t sB = botz ? 0 : HW_;
  const float* wp0 = w + (size_t)co0 * (C_ * 9);
  const float* wp1 = w + (size_t)co1 * (C_ * 9);

  float acc0[8][9], acc1[8][9];        // acc0 -> co0, acc1 -> co1 (same px strip)
#pragma unroll
  for (int p = 0; p < 8; ++p)
#pragma unroll
    for (int t = 0; t < 9; ++t) { acc0[p][t] = 0.f; acc1[p][t] = 0.f; }

  for (int ci = 0; ci < C_; ++ci) {
    float4 tA = ((const float4*)pT)[0], tB4 = ((const float4*)pT)[1];
    float4 mA = ((const float4*)pM)[0], mB4 = ((const float4*)pM)[1];
    float4 bA = ((const float4*)pB)[0], bB4 = ((const float4*)pB)[1];
    pT += sT; pM += HW_; pB += sB;

    float T[10], M[10], Bo[10];
    T[1]=tA.x;  T[2]=tA.y;  T[3]=tA.z;  T[4]=tA.w;  T[5]=tB4.x;  T[6]=tB4.y;  T[7]=tB4.z;  T[8]=tB4.w;
    M[1]=mA.x;  M[2]=mA.y;  M[3]=mA.z;  M[4]=mA.w;  M[5]=mB4.x;  M[6]=mB4.y;  M[7]=mB4.z;  M[8]=mB4.w;
    Bo[1]=bA.x; Bo[2]=bA.y; Bo[3]=bA.z; Bo[4]=bA.w; Bo[5]=bB4.x; Bo[6]=bB4.y; Bo[7]=bB4.z; Bo[8]=bB4.w;

    T[0]  = __shfl_up(T[8], 1u);    if (lef0) T[0]  = 0.f;
    T[9]  = __shfl_down(T[1], 1u);  if (rig0) T[9]  = 0.f;
    M[0]  = __shfl_up(M[8], 1u);    if (lef0) M[0]  = 0.f;
    M[9]  = __shfl_down(M[1], 1u);  if (rig0) M[9]  = 0.f;
    Bo[0] = __shfl_up(Bo[8], 1u);   if (lef0) Bo[0] = 0.f;
    Bo[9] = __shfl_down(Bo[1], 1u); if (rig0) Bo[9] = 0.f;

    float w9a[9], w9b[9];
#pragma unroll
    for (int t = 0; t < 9; ++t) w9a[t] = wp0[ci * 9 + t];   // wave-uniform -> s_load
#pragma unroll
    for (int t = 0; t < 9; ++t) w9b[t] = wp1[ci * 9 + t];

#pragma unroll
    for (int p = 0; p < 8; ++p) {
      acc0[p][0] = fmaf(w9a[0], T[p],     acc0[p][0]);
      acc0[p][1] = fmaf(w9a[1], T[p+1],   acc0[p][1]);
      acc0[p][2] = fmaf(w9a[2], T[p+2],   acc0[p][2]);
      acc0[p][3] = fmaf(w9a[3], M[p],     acc0[p][3]);
      acc0[p][4] = fmaf(w9a[4], M[p+1],   acc0[p][4]);
      acc0[p][5] = fmaf(w9a[5], M[p+2],   acc0[p][5]);
      acc0[p][6] = fmaf(w9a[6], Bo[p],    acc0[p][6]);
      acc0[p][7] = fmaf(w9a[7], Bo[p+1],  acc0[p][7]);
      acc0[p][8] = fmaf(w9a[8], Bo[p+2],  acc0[p][8]);
      acc1[p][0] = fmaf(w9b[0], T[p],     acc1[p][0]);
      acc1[p][1] = fmaf(w9b[1], T[p+1],   acc1[p][1]);
      acc1[p][2] = fmaf(w9b[2], T[p+2],   acc1[p][2]);
      acc1[p][3] = fmaf(w9b[3], M[p],     acc1[p][3]);
      acc1[p][4] = fmaf(w9b[4], M[p+1],   acc1[p][4]);
      acc1[p][5] = fmaf(w9b[5], M[p+2],   acc1[p][5]);
      acc1[p][6] = fmaf(w9b[6], Bo[p],    acc1[p][6]);
      acc1[p][7] = fmaf(w9b[7], Bo[p+1],  acc1[p][7]);
      acc1[p][8] = fmaf(w9b[8], Bo[p+2],  acc1[p][8]);
    }
  }

  float bv0 = bias[co0], bv1 = bias[co1];
  float ov0[8], ov1[8];
#pragma unroll
  for (int p = 0; p < 8; ++p) {
    float a = 0.f;
#pragma unroll
    for (int t = 0; t < 9; ++t) a = a + acc0[p][t];  // tap-ordered, left-assoc
    a = a + bv0;
    ov0[p] = a > 0.f ? a : 0.f;
    float c = 0.f;
#pragma unroll
    for (int t = 0; t < 9; ++t) c = c + acc1[p][t];
    c = c + bv1;
    ov1[p] = c > 0.f ? c : 0.f;
  }
  float* f0 = feats + ((size_t)b * C_ + co0) * HW_ + (size_t)gr * W_ + c0;
  float* f1 = feats + ((size_t)b * C_ + co1) * HW_ + (size_t)gr * W_ + c0;
  ((float4*)f0)[0] = make_float4(ov0[0], ov0[1], ov0[2], ov0[3]);
  ((float4*)f0)[1] = make_float4(ov0[4], ov0[5], ov0[6], ov0[7]);
  ((float4*)f1)[0] = make_float4(ov1[0], ov1[1], ov1[2], ov1[3]);
  ((float4*)f1)[1] = make_float4(ov1[4], ov1[5], ov1[6], ov1[7]);
}

// ---------------- K2: 1x1 convs, 3-way channel split (15 chains/thread), bit-exact ----------------
__global__ __launch_bounds__(256) void conv1_split3(
    const float* __restrict__ feats,
    const float* __restrict__ box_w, const float* __restrict__ box_b,
    const float* __restrict__ obj_w, const float* __restrict__ obj_b,
    float* __restrict__ tbox, float* __restrict__ scores) {
#pragma clang fp contract(off)
  int gidx = blockIdx.x * 256 + threadIdx.x;   // [0, 3*B_*HW_)
  int cgrp = gidx >> 15;                        // 0..2
  int rem  = gidx & 32767;
  int b  = rem >> 12;
  int hw = rem & 4095;
  int cbase = cgrp * 15;
  const float* f = feats + (size_t)b * C_ * HW_ + hw;
  const float* wrow[15];
#pragma unroll
  for (int jj = 0; jj < 15; ++jj) {
    int c = cbase + jj;
    wrow[jj] = (c < 36) ? (box_w + (size_t)c * C_) : (obj_w + (size_t)(c - 36) * C_);
  }
  float acc[15];
#pragma unroll
  for (int jj = 0; jj < 15; ++jj) acc[jj] = 0.f;
  for (int ci = 0; ci < C_; ++ci) {
    float fv = f[(size_t)ci * HW_];
#pragma unroll
    for (int jj = 0; jj < 15; ++jj)
      acc[jj] = fmaf(wrow[jj][ci], fv, acc[jj]);
  }
#pragma unroll
  for (int jj = 0; jj < 15; ++jj) {
    int c = cbase + jj;
    if (c < 36) {
      int k = c / 9, a = c - k * 9;
      tbox[(size_t)b * 4 * SITES + (size_t)k * SITES + (size_t)a * HW_ + hw] = acc[jj] + box_b[c];
    } else {
      int a = c - 36;
      scores[(size_t)b * SITES + (size_t)a * HW_ + hw] = acc[jj] + obj_b[a];
    }
  }
}

// ---------------- K3: exact radix-select of the 1000th-smallest key per batch ----------------
__global__ __launch_bounds__(1024) void radix_select(
    const float* __restrict__ scores, unsigned* __restrict__ Kout,
    int* __restrict__ needEq, int* __restrict__ cnt, int* __restrict__ eqCnt) {
  int b = blockIdx.x;
  const float* s = scores + (size_t)b * SITES;
  __shared__ unsigned hist[256];
  __shared__ unsigned sh_prefix, sh_mask, sh_cless;
  __shared__ int sh_target;
  if (threadIdx.x == 0) { sh_prefix = 0; sh_mask = 0; sh_target = NPOST - 1; sh_cless = 0; }
  for (int shift = 24; shift >= 0; shift -= 8) {
    if (threadIdx.x < 256) hist[threadIdx.x] = 0;
    __syncthreads();
    unsigned prefix = sh_prefix, mask = sh_mask;
    for (int i = threadIdx.x; i < SITES; i += 1024) {
      unsigned k = keyf(s[i]);
      if ((k & mask) == prefix) atomicAdd(&hist[(k >> shift) & 255u], 1u);
    }
    __syncthreads();
    if (threadIdx.x == 0) {
      unsigned cum = 0; int t = sh_target; int v = 0;
      for (; v < 256; ++v) {
        unsigned h = hist[v];
        if (cum + h > (unsigned)t) break;
        cum += h;
      }
      sh_prefix |= ((unsigned)v) << shift;
      sh_mask   |= 0xFFu << shift;
      sh_target  = t - (int)cum;
      sh_cless  += cum;
    }
    __syncthreads();
  }
  if (threadIdx.x == 0) {
    Kout[b] = sh_prefix;
    needEq[b] = NPOST - (int)sh_cless;
    cnt[b] = 0;
    eqCnt[b] = 0;
  }
}

// ---------------- K4: compact k<K sites; collect k==K sites ----------------
__global__ __launch_bounds__(256) void compact_sel(
    const float* __restrict__ scores, const unsigned* __restrict__ Kout,
    int* __restrict__ cnt, int* __restrict__ sel,
    int* __restrict__ eqCnt, int* __restrict__ eqList) {
  int b = blockIdx.x / 144;
  int i = (blockIdx.x % 144) * 256 + threadIdx.x;
  unsigned K = Kout[b];
  unsigned k = keyf(scores[(size_t)b * SITES + i]);
  if (k < K) {
    int pos = atomicAdd(&cnt[b], 1);
    sel[b * 1024 + pos] = i;               // arbitrary order: order_decode re-sorts
  } else if (k == K) {
    int e = atomicAdd(&eqCnt[b], 1);
    if (e < 4096) eqList[b * 4096 + e] = i;
  }
}

// ---------------- K4b: take the needEq smallest-index equal-key sites ----------------
__global__ __launch_bounds__(256) void fix_eq(
    const int* __restrict__ cnt, const int* __restrict__ needEq,
    const int* __restrict__ eqCnt, const int* __restrict__ eqList,
    int* __restrict__ sel) {
  int b = blockIdx.x;
  int E = eqCnt[b]; if (E > 4096) E = 4096;
  int need = needEq[b];
  int base = cnt[b];
  const int* el = eqList + b * 4096;
  for (int t = threadIdx.x; t < E; t += 256) {
    int site = el[t];
    int rank = 0;
    for (int q = 0; q < E; ++q) rank += (el[q] < site);
    if (rank < need) sel[b * 1024 + base + rank] = site;
  }
}

// ---------------- K5: descending order + fused decode, 8 blocks/batch (125 ranks each) ----------------
__global__ __launch_bounds__(128) void order_decode(
    const float* __restrict__ scores, const int* __restrict__ sel,
    const float* __restrict__ tbox, float* __restrict__ s2, float* __restrict__ b2) {
#pragma clang fp contract(off)
  int b   = blockIdx.x >> 3;
  int r   = ((blockIdx.x & 7) * 125) + threadIdx.x;   // 125 ranks per block
  __shared__ float ss[NPOST];
  __shared__ int st[NPOST];
  for (int t = threadIdx.x; t < NPOST; t += 128) {
    int site = sel[b * 1024 + t];
    st[t] = site;
    ss[t] = scores[(size_t)b * SITES + site];
  }
  __syncthreads();
  if (threadIdx.x < 125) {
    float sr = ss[r]; int sir = st[r];
    int d = 0;
    for (int q = 0; q < NPOST; ++q) {
      float sq = ss[q];
      d += (int)((sq > sr) || (sq == sr && st[q] < sir));
    }
    s2[(size_t)b * NPOST + d] = sr;
    int site = sir;
    int a = site / HW_;
    int hw = site - a * HW_;
    int h = hw / W_, wc = hw - h * W_;
    int sidx = a / 3, ridx = a - sidx * 3;
    float scale = (sidx == 0) ? 128.f : ((sidx == 1) ? 256.f : 512.f);
    float ratio = (ridx == 0) ? 0.5f : ((ridx == 1) ? 1.0f : 2.0f);
    float sq = sqrtf(ratio);
    float wsa = scale / sq;
    float hsa = scale * sq;
    float cx = ((float)wc + 0.5f) * 16.f;
    float cy = ((float)h + 0.5f) * 16.f;
    float ax1 = cx - wsa * 0.5f;
    float ay1 = cy - hsa * 0.5f;
    float ax2 = cx + wsa * 0.5f;
    float ay2 = cy + hsa * 0.5f;
    float aw = ax2 - ax1, ah = ay2 - ay1;
    float m1 = 0.5f * aw, m2 = 0.5f * ah;
    float acx = ax1 + m1, acy = ay1 + m2;
    const float* tb = tbox + (size_t)b * 4 * SITES + site;
    float t0 = tb[0];
    float t1 = tb[SITES];
    float t2 = tb[2 * (size_t)SITES];
    float t3 = tb[3 * (size_t)SITES];
    if (t2 < -XCLIPF) t2 = -XCLIPF;
    if (t2 > XCLIPF) t2 = XCLIPF;
    if (t3 < -XCLIPF) t3 = -XCLIPF;
    if (t3 > XCLIPF) t3 = XCLIPF;
    float pm0 = t0 * aw;  float pcx = pm0 + acx;
    float pm1 = t1 * ah;  float pcy = pm1 + acy;
    float pw = expf(t2) * aw;
    float ph = expf(t3) * ah;
    float hw0 = 0.5f * pw, hh0 = 0.5f * ph;
    float x1 = pcx - hw0, y1 = pcy - hh0;
    float x2 = pcx + hw0, y2 = pcy + hh0;
    x1 = x1 < 0.f ? 0.f : (x1 > IMGF ? IMGF : x1);
    y1 = y1 < 0.f ? 0.f : (y1 > IMGF ? IMGF : y1);
    x2 = x2 < 0.f ? 0.f : (x2 > IMGF ? IMGF : x2);
    y2 = y2 < 0.f ? 0.f : (y2 > IMGF ? IMGF : y2);
    float* o = b2 + ((size_t)b * NPOST + d) * 4;
    o[0] = x1; o[1] = y1; o[2] = x2; o[3] = y2;
  }
}

// ---------------- K6a: suppression bitmask, f32 exact op order; conflict-fixed mapping ----------
__global__ __launch_bounds__(256) void mask_kernel(
    const float* __restrict__ b2, unsigned long long* __restrict__ sup) {
#pragma clang fp contract(off)
  int b = blockIdx.x / 63;
  int i0 = (blockIdx.x % 63) * 16;
  __shared__ float bs[NPOST * 4];
  __shared__ float area[NPOST];
  for (int t = threadIdx.x; t < NPOST * 4; t += 256) bs[t] = b2[(size_t)b * NPOST * 4 + t];
  __syncthreads();
  for (int t = threadIdx.x; t < NPOST; t += 256)
    area[t] = (bs[t * 4 + 2] - bs[t * 4]) * (bs[t * 4 + 3] - bs[t * 4 + 1]);
  __syncthreads();
  int i = i0 + (threadIdx.x & 15);
  int wd = threadIdx.x >> 4;
  if (i >= NPOST) return;
  float ax1 = bs[i * 4], ay1 = bs[i * 4 + 1], ax2 = bs[i * 4 + 2], ay2 = bs[i * 4 + 3];
  float aa = area[i];
  unsigned long long m = 0;
  for (int bit = 0; bit < 64; ++bit) {
    int j = wd * 64 + bit;
    if (j > i && j < NPOST) {
      float lx = fmaxf(ax1, bs[j * 4]);
      float ly = fmaxf(ay1, bs[j * 4 + 1]);
      float rx = fminf(ax2, bs[j * 4 + 2]);
      float ry = fminf(ay2, bs[j * 4 + 3]);
      float iw = rx - lx; if (iw < 0.f) iw = 0.f;
      float ih = ry - ly; if (ih < 0.f) ih = 0.f;
      float inter = iw * ih;
      float denom = (aa + area[j]) - inter;
      float iou = inter / denom;
      if (iou > 0.7f) m |= 1ull << bit;
    }
  }
  sup[((size_t)b * NPOST + i) * 16 + wd] = m;
}

// ---------------- K6b: wave-synchronous NMS scan, 8-deep prefetch + compaction ----------------
__global__ __launch_bounds__(64) void nms_out(
    const unsigned long long* __restrict__ sup, const float* __restrict__ b2,
    const float* __restrict__ s2, float* __restrict__ out) {
  int b = blockIdx.x;
  int lane = threadIdx.x;
  unsigned long long kw = 0;
  if (lane < 16) kw = (lane < 15) ? ~0ull : ((1ull << 40) - 1);  // bits 960..999 valid
  const unsigned long long* ms = sup + (size_t)b * NPOST * 16;
  unsigned long long mb[8];
#pragma unroll
  for (int k = 0; k < 8; ++k)
    mb[k] = (lane < 16) ? ms[(size_t)k * 16 + lane] : 0ull;
  for (int i0 = 0; i0 < NPOST; i0 += 8) {          // 1000 = 8*125
    unsigned long long nb[8];
#pragma unroll
    for (int k = 0; k < 8; ++k) {
      int nx = i0 + 8 + k;
      nb[k] = (nx < NPOST && lane < 16) ? ms[(size_t)nx * 16 + lane] : 0ull;
    }
#pragma unroll
    for (int k = 0; k < 8; ++k) {
      int i = i0 + k;
      unsigned long long w = __shfl(kw, i >> 6, 64);  // broadcast word holding bit i
      if ((w >> (i & 63)) & 1ull) {                   // wave-uniform branch
        if (lane < 16) kw &= ~mb[k];                  // bit i never set in row i (j>i only)
      }
    }
#pragma unroll
    for (int k = 0; k < 8; ++k) mb[k] = nb[k];
  }
  __shared__ unsigned long long keeps[16];
  if (lane < 16) keeps[lane] = kw;
  __syncthreads();
  int total = 0;
#pragma unroll
  for (int k = 0; k < 16; ++k) total += __popcll(keeps[k]);
  for (int i = lane; i < NPOST; i += 64) {
    int w = i >> 6;
    int before = 0;
    for (int k = 0; k < w; ++k) before += __popcll(keeps[k]);
    before += __popcll(keeps[w] & ((1ull << (i & 63)) - 1));
    bool kept = (keeps[w] >> (i & 63)) & 1ull;
    if (kept) {
      size_t ob = (size_t)b * (NPOST * 5) + (size_t)before * 5;
      const float* src = b2 + ((size_t)b * NPOST + i) * 4;
      out[ob + 0] = src[0];
      out[ob + 1] = src[1];
      out[ob + 2] = src[2];
      out[ob + 3] = src[3];
      out[ob + 4] = s2[(size_t)b * NPOST + i];
    }
    if (i >= total) {
      size_t ob = (size_t)b * (NPOST * 5) + (size_t)i * 5;
      for (int c = 0; c < 5; ++c) out[ob + c] = 0.f;
    }
  }
}

extern "C" void kernel_launch(void* const* d_in, const int* in_sizes, int n_in,
                              void* d_out, int out_size, void* d_ws, size_t ws_size,
                              hipStream_t stream) {
  const float *x = nullptr, *conv_w = nullptr, *conv_b = nullptr,
              *box_w = nullptr, *box_b = nullptr, *obj_w = nullptr, *obj_b = nullptr;
  for (int i = 0; i < n_in; ++i) {
    switch (in_sizes[i]) {
      case 8388608: x = (const float*)d_in[i]; break;
      case 589824:  conv_w = (const float*)d_in[i]; break;
      case 256:     conv_b = (const float*)d_in[i]; break;
      case 9216:    box_w = (const float*)d_in[i]; break;
      case 36:      box_b = (const float*)d_in[i]; break;
      case 2304:    obj_w = (const float*)d_in[i]; break;
      case 9:       obj_b = (const float*)d_in[i]; break;
    }
  }
  float* out = (float*)d_out;

  char* p = (char*)d_ws;
  auto alloc = [&](size_t n) { char* q = p; p += (n + 255) & ~255ull; return (void*)q; };
  float* feats  = (float*)alloc((size_t)B_ * C_ * HW_ * 4);       // 33.55 MB
  float* tbox   = (float*)alloc((size_t)B_ * 4 * SITES * 4);      // 4.72 MB
  float* scores = (float*)alloc((size_t)B_ * SITES * 4);          // 1.18 MB
  float* zrow   = (float*)alloc(256);                              // zero halo row
  unsigned* Kout = (unsigned*)alloc(B_ * 4);
  int* needEq    = (int*)alloc(B_ * 4);
  int* cnt       = (int*)alloc(B_ * 4);
  int* eqCnt     = (int*)alloc(B_ * 4);
  int* eqList    = (int*)alloc((size_t)B_ * 4096 * 4);
  int* sel       = (int*)alloc((size_t)B_ * 1024 * 4);
  float* s2      = (float*)alloc((size_t)B_ * NPOST * 4);
  float* b2      = (float*)alloc((size_t)B_ * NPOST * 4 * 4);
  unsigned long long* sup = (unsigned long long*)alloc((size_t)B_ * NPOST * 16 * 8); // 1.02 MB

  hipMemsetAsync(zrow, 0, 256, stream);
  hipLaunchKernelGGL(conv3_2co, dim3(B_ * (C_ / 2) * 2), dim3(256), 0, stream,
                     x, conv_w, conv_b, zrow, feats);
  hipLaunchKernelGGL(conv1_split3, dim3(3 * B_ * HW_ / 256), dim3(256), 0, stream,
                     feats, box_w, box_b, obj_w, obj_b, tbox, scores);
  hipLaunchKernelGGL(radix_select, dim3(B_), dim3(1024), 0, stream,
                     scores, Kout, needEq, cnt, eqCnt);
  hipLaunchKernelGGL(compact_sel, dim3(B_ * 144), dim3(256), 0, stream,
                     scores, Kout, cnt, sel, eqCnt, eqList);
  hipLaunchKernelGGL(fix_eq, dim3(B_), dim3(256), 0, stream,
                     cnt, needEq, eqCnt, eqList, sel);
  hipLaunchKernelGGL(order_decode, dim3(B_ * 8), dim3(128), 0, stream,
                     scores, sel, tbox, s2, b2);
  hipLaunchKernelGGL(mask_kernel, dim3(B_ * 63), dim3(256), 0, stream, b2, sup);
  hipLaunchKernelGGL(nms_out, dim3(B_), dim3(64), 0, stream, sup, b2, s2, out);
}

// Round 15
// 1078.978 us; speedup vs baseline: 1.8264x; 1.0066x over previous
//
#include <hip/hip_runtime.h>

#define B_ 8
#define C_ 256
#define H_ 64
#define W_ 64
#define HW_ 4096
#define A_ 9
#define SITES 36864      // A_*HW_
#define NPOST 1000
#define XCLIPF 4.1351666f   // (float)4.135166556742356
#define IMGF 1024.0f

__device__ inline unsigned keyf(float v) {
  unsigned u = __float_as_uint(v);
  return (u & 0x80000000u) ? ~u : (u | 0x80000000u);  // ascending uint == ascending float
}

// ---------------- K1: 3x3 conv + bias + relu, bit-exact f32, 4 co x 4 px per thread ----------
// Validated shfl-strip family (r7/r12/r14). One 3-row x 4-wide window feeds FOUR output
// channels: 3 float4 loads/iter (48B), full horizontal halo via lane+-1 shfl (no edge
// loads), zrow stride-0 vertical halo (exact no-op). 144 FMA per 3 loads -> ~88% FMA
// issue fraction. Every (co,px,tap) fmaf chain over ci ascending and the tap-ordered
// left-assoc epilogue are verbatim the validated code. absmax 0.0 family.
// grid: B_*64*4 = 2048 blocks (XCD swizzle b=blk&7); 256 threads = 16 rows x 16 chunks.
__global__ __launch_bounds__(256, 2) void conv3_4co(
    const float* __restrict__ x, const float* __restrict__ w,
    const float* __restrict__ bias, const float* __restrict__ zrow,
    float* __restrict__ feats) {
#pragma clang fp contract(off)
  int b       = blockIdx.x & 7;        // XCD-affine (perf-only)
  int j       = blockIdx.x >> 3;       // 0..255
  int quad    = j & 63;                // co quad
  int quarter = j >> 6;                // 0..3 (16-row band)
  int co0 = quad << 2;
  int row16 = threadIdx.x >> 4;        // 0..15
  int chunk = threadIdx.x & 15;        // 0..15
  int gr = (quarter << 4) + row16;     // output row 0..63
  int c0 = chunk << 2;                 // col base (16B aligned)
  bool lef0 = (chunk == 0), rig0 = (chunk == 15);
  bool topz = (gr == 0), botz = (gr == 63);

  const float* xb = x + (size_t)b * C_ * HW_;
  const float* pT = topz ? zrow : (xb + (ptrdiff_t)(gr - 1) * W_ + c0);
  const float* pM = xb + (size_t)gr * W_ + c0;
  const float* pB = botz ? zrow : (xb + (size_t)(gr + 1) * W_ + c0);
  ptrdiff_t sT = topz ? 0 : HW_;
  ptrdiff_t sB = botz ? 0 : HW_;
  const float* wp0 = w + (size_t)(co0 + 0) * (C_ * 9);
  const float* wp1 = w + (size_t)(co0 + 1) * (C_ * 9);
  const float* wp2 = w + (size_t)(co0 + 2) * (C_ * 9);
  const float* wp3 = w + (size_t)(co0 + 3) * (C_ * 9);

  float acc[4][4][9];                  // [co][px][tap]
#pragma unroll
  for (int q = 0; q < 4; ++q)
#pragma unroll
    for (int p = 0; p < 4; ++p)
#pragma unroll
      for (int t = 0; t < 9; ++t) acc[q][p][t] = 0.f;

  for (int ci = 0; ci < C_; ++ci) {
    float4 tA = ((const float4*)pT)[0];
    float4 mA = ((const float4*)pM)[0];
    float4 bA = ((const float4*)pB)[0];
    pT += sT; pM += HW_; pB += sB;

    float T[6], M[6], Bo[6];           // cols c0-1 .. c0+4
    T[1]=tA.x;  T[2]=tA.y;  T[3]=tA.z;  T[4]=tA.w;
    M[1]=mA.x;  M[2]=mA.y;  M[3]=mA.z;  M[4]=mA.w;
    Bo[1]=bA.x; Bo[2]=bA.y; Bo[3]=bA.z; Bo[4]=bA.w;

    T[0]  = __shfl_up(T[4], 1u);    if (lef0) T[0]  = 0.f;
    T[5]  = __shfl_down(T[1], 1u);  if (rig0) T[5]  = 0.f;
    M[0]  = __shfl_up(M[4], 1u);    if (lef0) M[0]  = 0.f;
    M[5]  = __shfl_down(M[1], 1u);  if (rig0) M[5]  = 0.f;
    Bo[0] = __shfl_up(Bo[4], 1u);   if (lef0) Bo[0] = 0.f;
    Bo[5] = __shfl_down(Bo[1], 1u); if (rig0) Bo[5] = 0.f;

    float w9[4][9];
#pragma unroll
    for (int t = 0; t < 9; ++t) w9[0][t] = wp0[ci * 9 + t];  // wave-uniform -> s_load
#pragma unroll
    for (int t = 0; t < 9; ++t) w9[1][t] = wp1[ci * 9 + t];
#pragma unroll
    for (int t = 0; t < 9; ++t) w9[2][t] = wp2[ci * 9 + t];
#pragma unroll
    for (int t = 0; t < 9; ++t) w9[3][t] = wp3[ci * 9 + t];

#pragma unroll
    for (int q = 0; q < 4; ++q)
#pragma unroll
      for (int p = 0; p < 4; ++p) {
        acc[q][p][0] = fmaf(w9[q][0], T[p],     acc[q][p][0]);
        acc[q][p][1] = fmaf(w9[q][1], T[p+1],   acc[q][p][1]);
        acc[q][p][2] = fmaf(w9[q][2], T[p+2],   acc[q][p][2]);
        acc[q][p][3] = fmaf(w9[q][3], M[p],     acc[q][p][3]);
        acc[q][p][4] = fmaf(w9[q][4], M[p+1],   acc[q][p][4]);
        acc[q][p][5] = fmaf(w9[q][5], M[p+2],   acc[q][p][5]);
        acc[q][p][6] = fmaf(w9[q][6], Bo[p],    acc[q][p][6]);
        acc[q][p][7] = fmaf(w9[q][7], Bo[p+1],  acc[q][p][7]);
        acc[q][p][8] = fmaf(w9[q][8], Bo[p+2],  acc[q][p][8]);
      }
  }

#pragma unroll
  for (int q = 0; q < 4; ++q) {
    float bv = bias[co0 + q];
    float ov[4];
#pragma unroll
    for (int p = 0; p < 4; ++p) {
      float a = 0.f;
#pragma unroll
      for (int t = 0; t < 9; ++t) a = a + acc[q][p][t];  // tap-ordered, left-assoc
      a = a + bv;
      ov[p] = a > 0.f ? a : 0.f;
    }
    float4* fo = (float4*)(feats + ((size_t)b * C_ + co0 + q) * HW_ + (size_t)gr * W_ + c0);
    fo[0] = make_float4(ov[0], ov[1], ov[2], ov[3]);
  }
}

// ---------------- K2: 1x1 convs, 3-way channel split (15 chains/thread), bit-exact ----------------
__global__ __launch_bounds__(256) void conv1_split3(
    const float* __restrict__ feats,
    const float* __restrict__ box_w, const float* __restrict__ box_b,
    const float* __restrict__ obj_w, const float* __restrict__ obj_b,
    float* __restrict__ tbox, float* __restrict__ scores) {
#pragma clang fp contract(off)
  int gidx = blockIdx.x * 256 + threadIdx.x;   // [0, 3*B_*HW_)
  int cgrp = gidx >> 15;                        // 0..2
  int rem  = gidx & 32767;
  int b  = rem >> 12;
  int hw = rem & 4095;
  int cbase = cgrp * 15;
  const float* f = feats + (size_t)b * C_ * HW_ + hw;
  const float* wrow[15];
#pragma unroll
  for (int jj = 0; jj < 15; ++jj) {
    int c = cbase + jj;
    wrow[jj] = (c < 36) ? (box_w + (size_t)c * C_) : (obj_w + (size_t)(c - 36) * C_);
  }
  float acc[15];
#pragma unroll
  for (int jj = 0; jj < 15; ++jj) acc[jj] = 0.f;
  for (int ci = 0; ci < C_; ++ci) {
    float fv = f[(size_t)ci * HW_];
#pragma unroll
    for (int jj = 0; jj < 15; ++jj)
      acc[jj] = fmaf(wrow[jj][ci], fv, acc[jj]);
  }
#pragma unroll
  for (int jj = 0; jj < 15; ++jj) {
    int c = cbase + jj;
    if (c < 36) {
      int k = c / 9, a = c - k * 9;
      tbox[(size_t)b * 4 * SITES + (size_t)k * SITES + (size_t)a * HW_ + hw] = acc[jj] + box_b[c];
    } else {
      int a = c - 36;
      scores[(size_t)b * SITES + (size_t)a * HW_ + hw] = acc[jj] + obj_b[a];
    }
  }
}

// ---------------- K3: exact radix-select of the 1000th-smallest key per batch ----------------
__global__ __launch_bounds__(1024) void radix_select(
    const float* __restrict__ scores, unsigned* __restrict__ Kout,
    int* __restrict__ needEq, int* __restrict__ cnt, int* __restrict__ eqCnt) {
  int b = blockIdx.x;
  const float* s = scores + (size_t)b * SITES;
  __shared__ unsigned hist[256];
  __shared__ unsigned sh_prefix, sh_mask, sh_cless;
  __shared__ int sh_target;
  if (threadIdx.x == 0) { sh_prefix = 0; sh_mask = 0; sh_target = NPOST - 1; sh_cless = 0; }
  for (int shift = 24; shift >= 0; shift -= 8) {
    if (threadIdx.x < 256) hist[threadIdx.x] = 0;
    __syncthreads();
    unsigned prefix = sh_prefix, mask = sh_mask;
    for (int i = threadIdx.x; i < SITES; i += 1024) {
      unsigned k = keyf(s[i]);
      if ((k & mask) == prefix) atomicAdd(&hist[(k >> shift) & 255u], 1u);
    }
    __syncthreads();
    if (threadIdx.x == 0) {
      unsigned cum = 0; int t = sh_target; int v = 0;
      for (; v < 256; ++v) {
        unsigned h = hist[v];
        if (cum + h > (unsigned)t) break;
        cum += h;
      }
      sh_prefix |= ((unsigned)v) << shift;
      sh_mask   |= 0xFFu << shift;
      sh_target  = t - (int)cum;
      sh_cless  += cum;
    }
    __syncthreads();
  }
  if (threadIdx.x == 0) {
    Kout[b] = sh_prefix;
    needEq[b] = NPOST - (int)sh_cless;
    cnt[b] = 0;
    eqCnt[b] = 0;
  }
}

// ---------------- K4: compact k<K sites; collect k==K sites ----------------
__global__ __launch_bounds__(256) void compact_sel(
    const float* __restrict__ scores, const unsigned* __restrict__ Kout,
    int* __restrict__ cnt, int* __restrict__ sel,
    int* __restrict__ eqCnt, int* __restrict__ eqList) {
  int b = blockIdx.x / 144;
  int i = (blockIdx.x % 144) * 256 + threadIdx.x;
  unsigned K = Kout[b];
  unsigned k = keyf(scores[(size_t)b * SITES + i]);
  if (k < K) {
    int pos = atomicAdd(&cnt[b], 1);
    sel[b * 1024 + pos] = i;               // arbitrary order: order_decode re-sorts
  } else if (k == K) {
    int e = atomicAdd(&eqCnt[b], 1);
    if (e < 4096) eqList[b * 4096 + e] = i;
  }
}

// ---------------- K4b: take the needEq smallest-index equal-key sites ----------------
__global__ __launch_bounds__(256) void fix_eq(
    const int* __restrict__ cnt, const int* __restrict__ needEq,
    const int* __restrict__ eqCnt, const int* __restrict__ eqList,
    int* __restrict__ sel) {
  int b = blockIdx.x;
  int E = eqCnt[b]; if (E > 4096) E = 4096;
  int need = needEq[b];
  int base = cnt[b];
  const int* el = eqList + b * 4096;
  for (int t = threadIdx.x; t < E; t += 256) {
    int site = el[t];
    int rank = 0;
    for (int q = 0; q < E; ++q) rank += (el[q] < site);
    if (rank < need) sel[b * 1024 + base + rank] = site;
  }
}

// ---------------- K5: descending order + fused decode, 8 blocks/batch (125 ranks each) ----------------
__global__ __launch_bounds__(128) void order_decode(
    const float* __restrict__ scores, const int* __restrict__ sel,
    const float* __restrict__ tbox, float* __restrict__ s2, float* __restrict__ b2) {
#pragma clang fp contract(off)
  int b   = blockIdx.x >> 3;
  int r   = ((blockIdx.x & 7) * 125) + threadIdx.x;   // 125 ranks per block
  __shared__ float ss[NPOST];
  __shared__ int st[NPOST];
  for (int t = threadIdx.x; t < NPOST; t += 128) {
    int site = sel[b * 1024 + t];
    st[t] = site;
    ss[t] = scores[(size_t)b * SITES + site];
  }
  __syncthreads();
  if (threadIdx.x < 125) {
    float sr = ss[r]; int sir = st[r];
    int d = 0;
    for (int q = 0; q < NPOST; ++q) {
      float sq = ss[q];
      d += (int)((sq > sr) || (sq == sr && st[q] < sir));
    }
    s2[(size_t)b * NPOST + d] = sr;
    int site = sir;
    int a = site / HW_;
    int hw = site - a * HW_;
    int h = hw / W_, wc = hw - h * W_;
    int sidx = a / 3, ridx = a - sidx * 3;
    float scale = (sidx == 0) ? 128.f : ((sidx == 1) ? 256.f : 512.f);
    float ratio = (ridx == 0) ? 0.5f : ((ridx == 1) ? 1.0f : 2.0f);
    float sq = sqrtf(ratio);
    float wsa = scale / sq;
    float hsa = scale * sq;
    float cx = ((float)wc + 0.5f) * 16.f;
    float cy = ((float)h + 0.5f) * 16.f;
    float ax1 = cx - wsa * 0.5f;
    float ay1 = cy - hsa * 0.5f;
    float ax2 = cx + wsa * 0.5f;
    float ay2 = cy + hsa * 0.5f;
    float aw = ax2 - ax1, ah = ay2 - ay1;
    float m1 = 0.5f * aw, m2 = 0.5f * ah;
    float acx = ax1 + m1, acy = ay1 + m2;
    const float* tb = tbox + (size_t)b * 4 * SITES + site;
    float t0 = tb[0];
    float t1 = tb[SITES];
    float t2 = tb[2 * (size_t)SITES];
    float t3 = tb[3 * (size_t)SITES];
    if (t2 < -XCLIPF) t2 = -XCLIPF;
    if (t2 > XCLIPF) t2 = XCLIPF;
    if (t3 < -XCLIPF) t3 = -XCLIPF;
    if (t3 > XCLIPF) t3 = XCLIPF;
    float pm0 = t0 * aw;  float pcx = pm0 + acx;
    float pm1 = t1 * ah;  float pcy = pm1 + acy;
    float pw = expf(t2) * aw;
    float ph = expf(t3) * ah;
    float hw0 = 0.5f * pw, hh0 = 0.5f * ph;
    float x1 = pcx - hw0, y1 = pcy - hh0;
    float x2 = pcx + hw0, y2 = pcy + hh0;
    x1 = x1 < 0.f ? 0.f : (x1 > IMGF ? IMGF : x1);
    y1 = y1 < 0.f ? 0.f : (y1 > IMGF ? IMGF : y1);
    x2 = x2 < 0.f ? 0.f : (x2 > IMGF ? IMGF : x2);
    y2 = y2 < 0.f ? 0.f : (y2 > IMGF ? IMGF : y2);
    float* o = b2 + ((size_t)b * NPOST + d) * 4;
    o[0] = x1; o[1] = y1; o[2] = x2; o[3] = y2;
  }
}

// ---------------- K6a: suppression bitmask, f32 exact op order; conflict-fixed mapping ----------
__global__ __launch_bounds__(256) void mask_kernel(
    const float* __restrict__ b2, unsigned long long* __restrict__ sup) {
#pragma clang fp contract(off)
  int b = blockIdx.x / 63;
  int i0 = (blockIdx.x % 63) * 16;
  __shared__ float bs[NPOST * 4];
  __shared__ float area[NPOST];
  for (int t = threadIdx.x; t < NPOST * 4; t += 256) bs[t] = b2[(size_t)b * NPOST * 4 + t];
  __syncthreads();
  for (int t = threadIdx.x; t < NPOST; t += 256)
    area[t] = (bs[t * 4 + 2] - bs[t * 4]) * (bs[t * 4 + 3] - bs[t * 4 + 1]);
  __syncthreads();
  int i = i0 + (threadIdx.x & 15);
  int wd = threadIdx.x >> 4;
  if (i >= NPOST) return;
  float ax1 = bs[i * 4], ay1 = bs[i * 4 + 1], ax2 = bs[i * 4 + 2], ay2 = bs[i * 4 + 3];
  float aa = area[i];
  unsigned long long m = 0;
  for (int bit = 0; bit < 64; ++bit) {
    int j = wd * 64 + bit;
    if (j > i && j < NPOST) {
      float lx = fmaxf(ax1, bs[j * 4]);
      float ly = fmaxf(ay1, bs[j * 4 + 1]);
      float rx = fminf(ax2, bs[j * 4 + 2]);
      float ry = fminf(ay2, bs[j * 4 + 3]);
      float iw = rx - lx; if (iw < 0.f) iw = 0.f;
      float ih = ry - ly; if (ih < 0.f) ih = 0.f;
      float inter = iw * ih;
      float denom = (aa + area[j]) - inter;
      float iou = inter / denom;
      if (iou > 0.7f) m |= 1ull << bit;
    }
  }
  sup[((size_t)b * NPOST + i) * 16 + wd] = m;
}

// ---------------- K6b: wave-synchronous NMS scan, 8-deep prefetch + compaction ----------------
__global__ __launch_bounds__(64) void nms_out(
    const unsigned long long* __restrict__ sup, const float* __restrict__ b2,
    const float* __restrict__ s2, float* __restrict__ out) {
  int b = blockIdx.x;
  int lane = threadIdx.x;
  unsigned long long kw = 0;
  if (lane < 16) kw = (lane < 15) ? ~0ull : ((1ull << 40) - 1);  // bits 960..999 valid
  const unsigned long long* ms = sup + (size_t)b * NPOST * 16;
  unsigned long long mb[8];
#pragma unroll
  for (int k = 0; k < 8; ++k)
    mb[k] = (lane < 16) ? ms[(size_t)k * 16 + lane] : 0ull;
  for (int i0 = 0; i0 < NPOST; i0 += 8) {          // 1000 = 8*125
    unsigned long long nb[8];
#pragma unroll
    for (int k = 0; k < 8; ++k) {
      int nx = i0 + 8 + k;
      nb[k] = (nx < NPOST && lane < 16) ? ms[(size_t)nx * 16 + lane] : 0ull;
    }
#pragma unroll
    for (int k = 0; k < 8; ++k) {
      int i = i0 + k;
      unsigned long long w = __shfl(kw, i >> 6, 64);  // broadcast word holding bit i
      if ((w >> (i & 63)) & 1ull) {                   // wave-uniform branch
        if (lane < 16) kw &= ~mb[k];                  // bit i never set in row i (j>i only)
      }
    }
#pragma unroll
    for (int k = 0; k < 8; ++k) mb[k] = nb[k];
  }
  __shared__ unsigned long long keeps[16];
  if (lane < 16) keeps[lane] = kw;
  __syncthreads();
  int total = 0;
#pragma unroll
  for (int k = 0; k < 16; ++k) total += __popcll(keeps[k]);
  for (int i = lane; i < NPOST; i += 64) {
    int w = i >> 6;
    int before = 0;
    for (int k = 0; k < w; ++k) before += __popcll(keeps[k]);
    before += __popcll(keeps[w] & ((1ull << (i & 63)) - 1));
    bool kept = (keeps[w] >> (i & 63)) & 1ull;
    if (kept) {
      size_t ob = (size_t)b * (NPOST * 5) + (size_t)before * 5;
      const float* src = b2 + ((size_t)b * NPOST + i) * 4;
      out[ob + 0] = src[0];
      out[ob + 1] = src[1];
      out[ob + 2] = src[2];
      out[ob + 3] = src[3];
      out[ob + 4] = s2[(size_t)b * NPOST + i];
    }
    if (i >= total) {
      size_t ob = (size_t)b * (NPOST * 5) + (size_t)i * 5;
      for (int c = 0; c < 5; ++c) out[ob + c] = 0.f;
    }
  }
}

extern "C" void kernel_launch(void* const* d_in, const int* in_sizes, int n_in,
                              void* d_out, int out_size, void* d_ws, size_t ws_size,
                              hipStream_t stream) {
  const float *x = nullptr, *conv_w = nullptr, *conv_b = nullptr,
              *box_w = nullptr, *box_b = nullptr, *obj_w = nullptr, *obj_b = nullptr;
  for (int i = 0; i < n_in; ++i) {
    switch (in_sizes[i]) {
      case 8388608: x = (const float*)d_in[i]; break;
      case 589824:  conv_w = (const float*)d_in[i]; break;
      case 256:     conv_b = (const float*)d_in[i]; break;
      case 9216:    box_w = (const float*)d_in[i]; break;
      case 36:      box_b = (const float*)d_in[i]; break;
      case 2304:    obj_w = (const float*)d_in[i]; break;
      case 9:       obj_b = (const float*)d_in[i]; break;
    }
  }
  float* out = (float*)d_out;

  char* p = (char*)d_ws;
  auto alloc = [&](size_t n) { char* q = p; p += (n + 255) & ~255ull; return (void*)q; };
  float* feats  = (float*)alloc((size_t)B_ * C_ * HW_ * 4);       // 33.55 MB
  float* tbox   = (float*)alloc((size_t)B_ * 4 * SITES * 4);      // 4.72 MB
  float* scores = (float*)alloc((size_t)B_ * SITES * 4);          // 1.18 MB
  float* zrow   = (float*)alloc(256);                              // zero halo row
  unsigned* Kout = (unsigned*)alloc(B_ * 4);
  int* needEq    = (int*)alloc(B_ * 4);
  int* cnt       = (int*)alloc(B_ * 4);
  int* eqCnt     = (int*)alloc(B_ * 4);
  int* eqList    = (int*)alloc((size_t)B_ * 4096 * 4);
  int* sel       = (int*)alloc((size_t)B_ * 1024 * 4);
  float* s2      = (float*)alloc((size_t)B_ * NPOST * 4);
  float* b2      = (float*)alloc((size_t)B_ * NPOST * 4 * 4);
  unsigned long long* sup = (unsigned long long*)alloc((size_t)B_ * NPOST * 16 * 8); // 1.02 MB

  hipMemsetAsync(zrow, 0, 256, stream);
  hipLaunchKernelGGL(conv3_4co, dim3(B_ * 64 * 4), dim3(256), 0, stream,
                     x, conv_w, conv_b, zrow, feats);
  hipLaunchKernelGGL(conv1_split3, dim3(3 * B_ * HW_ / 256), dim3(256), 0, stream,
                     feats, box_w, box_b, obj_w, obj_b, tbox, scores);
  hipLaunchKernelGGL(radix_select, dim3(B_), dim3(1024), 0, stream,
                     scores, Kout, needEq, cnt, eqCnt);
  hipLaunchKernelGGL(compact_sel, dim3(B_ * 144), dim3(256), 0, stream,
                     scores, Kout, cnt, sel, eqCnt, eqList);
  hipLaunchKernelGGL(fix_eq, dim3(B_), dim3(256), 0, stream,
                     cnt, needEq, eqCnt, eqList, sel);
  hipLaunchKernelGGL(order_decode, dim3(B_ * 8), dim3(128), 0, stream,
                     scores, sel, tbox, s2, b2);
  hipLaunchKernelGGL(mask_kernel, dim3(B_ * 63), dim3(256), 0, stream, b2, sup);
  hipLaunchKernelGGL(nms_out, dim3(B_), dim3(64), 0, stream, sup, b2, s2, out);
}